// Round 20
// baseline (152.562 us; speedup 1.0000x reference)
//
#include <hip/hip_runtime.h>
#include <hip/hip_bf16.h>

#define LSEQ 2048
#define NB   4
#define EMB  1024
#define NH   16
#define DH   64
#define BH   (NB*NH)   // 64 head-batches
#define SCALE 0.125f   // d^-0.5
#define CCH  8         // K-tile chunks per b (block-level, stride-interleaved)
#define LOG2E 1.4426950408889634f
#define NEG16LOG2E (-23.083120654223414f)   // -16*log2e (acc C-init)

typedef unsigned short ushort8 __attribute__((ext_vector_type(8)));
typedef unsigned short usht4 __attribute__((ext_vector_type(4)));   // ushort4 name taken by HIP
typedef __attribute__((ext_vector_type(8))) short bf16x8;    // MFMA A/B frag (8 bf16)
typedef __attribute__((ext_vector_type(4))) float f32x4;     // 16x16 C/D frag
typedef __attribute__((ext_vector_type(16))) float f32x16;   // 32x32 C/D frag
typedef __attribute__((ext_vector_type(2))) float f32x2;     // packed z/o acc

#define EXP2F(x) __builtin_amdgcn_exp2f(x)   // v_exp_f32 (HW exp2)

__device__ __forceinline__ unsigned short f_to_bf(float f) {
    unsigned int u = __float_as_uint(f);
    return (unsigned short)((u + 0x7fffu + ((u >> 16) & 1u)) >> 16);
}

__device__ __forceinline__ void gload_lds16(const void* g, void* l) {
    __builtin_amdgcn_global_load_lds(
        (const __attribute__((address_space(1))) unsigned int*)g,
        (__attribute__((address_space(3))) unsigned int*)l, 16, 0, 0);
}

// ---- prep: fused tobf16(wqkv) [blocks 0..1023] + wsum_part [1024..1151] ----
__global__ __launch_bounds__(256) void prep_kernel(const float* __restrict__ wqkv,
                                                   const float* __restrict__ wout,
                                                   unsigned short* __restrict__ wb,
                                                   float* __restrict__ wpart) {
    if (blockIdx.x < 1024) {
        int i = blockIdx.x * 256 + threadIdx.x;   // < 2*EMB*EMB/8
        const float4* p = reinterpret_cast<const float4*>(wqkv) + (size_t)i * 2;
        float4 a = p[0], b = p[1];
        ushort8 o;
        o[0] = f_to_bf(a.x); o[1] = f_to_bf(a.y); o[2] = f_to_bf(a.z); o[3] = f_to_bf(a.w);
        o[4] = f_to_bf(b.x); o[5] = f_to_bf(b.y); o[6] = f_to_bf(b.z); o[7] = f_to_bf(b.w);
        reinterpret_cast<ushort8*>(wb)[i] = o;
    } else {
        int bb = blockIdx.x - 1024;
        int fc = bb >> 2;
        int e  = (bb & 3) * 256 + threadIdx.x;
        float s = 0.f;
        #pragma unroll 8
        for (int f = fc * 32; f < fc * 32 + 32; ++f) s += wout[(size_t)f * EMB + e];
        wpart[(size_t)fc * EMB + e] = s;
    }
}

__global__ __launch_bounds__(256) void wsum_final_kernel(const float* __restrict__ wpart,
                                                         float* __restrict__ wsum) {
    int e = blockIdx.x * 256 + threadIdx.x;
    float s = 0.f;
    #pragma unroll
    for (int c = 0; c < 32; ++c) s += wpart[(size_t)c * EMB + e];
    wsum[e] = s;
}

// ---- wv_eff[h][e] = sum_j wqkv[2E + h*64 + j][e] * wsum[h*64+j] ----
__global__ void wveff_kernel(const float* __restrict__ wqkv, const float* __restrict__ wsum,
                             float* __restrict__ wveff) {
    int idx = blockIdx.x * 256 + threadIdx.x;   // h*EMB + e
    int h = idx >> 10, e = idx & 1023;
    float s = 0.f;
    #pragma unroll 8
    for (int j = 0; j < DH; ++j)
        s += wqkv[(size_t)(2 * EMB + h * DH + j) * EMB + e] * wsum[h * DH + j];
    wveff[idx] = s;
}

// ---- vw[b][m] = sum_e x[m,n,e]*wveff[h,e] + fused x->bf16, float4 loads ----
__global__ __launch_bounds__(256) void vw_kernel(const float* __restrict__ x,
                                                 const float* __restrict__ wveff,
                                                 float* __restrict__ vw,
                                                 unsigned short* __restrict__ xb) {
    int wave = threadIdx.x >> 6;
    int lane = threadIdx.x & 63;
    int r = blockIdx.x * 4 + wave;   // r = l*NB + n
    int n = r & 3, l = r >> 2;
    float acc[NH] = {};
    #pragma unroll
    for (int it = 0; it < 4; ++it) {
        int e = it * 256 + lane * 4;
        float4 xv = *reinterpret_cast<const float4*>(&x[(size_t)r * EMB + e]);
        usht4 o;
        o[0] = f_to_bf(xv.x); o[1] = f_to_bf(xv.y); o[2] = f_to_bf(xv.z); o[3] = f_to_bf(xv.w);
        *reinterpret_cast<usht4*>(&xb[(size_t)r * EMB + e]) = o;
        #pragma unroll
        for (int h = 0; h < NH; ++h) {
            float4 w = *reinterpret_cast<const float4*>(&wveff[h * EMB + e]);
            acc[h] += xv.x * w.x + xv.y * w.y + xv.z * w.z + xv.w * w.w;
        }
    }
    #pragma unroll
    for (int h = 0; h < NH; ++h) {
        float v = acc[h];
        #pragma unroll
        for (int off = 32; off > 0; off >>= 1) v += __shfl_down(v, off, 64);
        if (lane == 0) vw[(size_t)(n * NH + h) * LSEQ + l] = v;
    }
}

// ---- bf16 MFMA Q/K projection: PBK=64 dbuf, 8 waves (R18-exact) ----
#define PBM 128
#define PBN 128
#define PBK 64
#define BUFS ((PBM + PBN) * PBK)   // shorts per buffer (32 KB)

__device__ __forceinline__ void proj_stage(const unsigned short* __restrict__ xb,
                                           const unsigned short* __restrict__ wb,
                                           unsigned short* As, unsigned short* Bs,
                                           int r0, int c0, int k0, int wid, int srow, int sj) {
    #pragma unroll
    for (int i = 0; i < 2; ++i) {
        int seg = wid * 2 + i;                    // 16 segments of 8 rows
        gload_lds16(&xb[(size_t)(r0 + seg * 8 + srow) * EMB + k0 + sj], &As[seg * 8 * PBK]);
        gload_lds16(&wb[(size_t)(c0 + seg * 8 + srow) * EMB + k0 + sj], &Bs[seg * 8 * PBK]);
    }
}

__device__ __forceinline__ void proj_compute(const unsigned short* As, const unsigned short* Bs,
                                             int wr, int wc, int col, int g, f32x4 (&acc)[4][2]) {
    #pragma unroll
    for (int kk = 0; kk < 2; ++kk) {
        bf16x8 af[4], bff[2];
        #pragma unroll
        for (int m = 0; m < 4; ++m) {
            int row = wr * 64 + m * 16 + col;
            af[m] = *reinterpret_cast<const bf16x8*>(
                &As[row * PBK + (((kk * 4 + g) ^ (row & 7)) * 8)]);
        }
        #pragma unroll
        for (int n = 0; n < 2; ++n) {
            int row = wc * 32 + n * 16 + col;
            bff[n] = *reinterpret_cast<const bf16x8*>(
                &Bs[row * PBK + (((kk * 4 + g) ^ (row & 7)) * 8)]);
        }
        #pragma unroll
        for (int m = 0; m < 4; ++m)
            #pragma unroll
            for (int n = 0; n < 2; ++n)
                acc[m][n] = __builtin_amdgcn_mfma_f32_16x16x32_bf16(af[m], bff[n], acc[m][n], 0, 0, 0);
    }
}

__global__ __launch_bounds__(512) void proj_mfma(const unsigned short* __restrict__ xb,
                                                 const unsigned short* __restrict__ wb,
                                                 unsigned short* __restrict__ qws,
                                                 unsigned short* __restrict__ kws) {
    __shared__ unsigned short SMEM[2 * BUFS];   // 64 KB (dbuf)
    unsigned short* As0 = SMEM;
    unsigned short* Bs0 = SMEM + PBM * PBK;
    unsigned short* As1 = SMEM + BUFS;
    unsigned short* Bs1 = As1 + PBM * PBK;
    const int tid  = threadIdx.x;
    const int lane = tid & 63;
    const int wid  = tid >> 6;                 // 0..7
    const int wr   = wid >> 2, wc = wid & 3;   // 2x4 wave grid, wave tile 64x32
    const int d  = blockIdx.x;
    const int w  = (d & 7) * 128 + (d >> 3);
    const int r0 = (w >> 4) * PBM;
    const int c0 = (w & 15) * PBN;
    const int col  = lane & 15, g = lane >> 4;

    f32x4 acc[4][2];
    #pragma unroll
    for (int m = 0; m < 4; ++m)
        #pragma unroll
        for (int n = 0; n < 2; ++n) acc[m][n] = f32x4{0.f, 0.f, 0.f, 0.f};

    const int srow = lane >> 3;
    const int sj   = ((lane & 7) ^ (lane >> 3)) * 8;

    proj_stage(xb, wb, As0, Bs0, r0, c0, 0, wid, srow, sj);
    __syncthreads();
    #pragma unroll 1
    for (int t = 0; t < 16; t += 2) {
        proj_stage(xb, wb, As1, Bs1, r0, c0, (t + 1) * PBK, wid, srow, sj);
        proj_compute(As0, Bs0, wr, wc, col, g, acc);
        __syncthreads();
        if (t + 2 < 16)
            proj_stage(xb, wb, As0, Bs0, r0, c0, (t + 2) * PBK, wid, srow, sj);
        proj_compute(As1, Bs1, wr, wc, col, g, acc);
        __syncthreads();
    }

    const float scl = (c0 < EMB) ? SCALE * LOG2E : 1.0f;   // block is purely Q or K
    #pragma unroll
    for (int m = 0; m < 4; ++m) {
        #pragma unroll
        for (int n = 0; n < 2; ++n) {
            #pragma unroll
            for (int j = 0; j < 4; ++j) {
                int row = wr * 64 + m * 16 + g * 4 + j;
                int cc  = wc * 32 + n * 16 + col;
                SMEM[row * 128 + (((cc >> 3) ^ (row & 7)) * 8) + (cc & 7)] =
                    f_to_bf(acc[m][n][j] * scl);
            }
        }
    }
    __syncthreads();
    #pragma unroll
    for (int pass = 0; pass < 4; ++pass) {
        int unit = pass * 64 + (tid >> 3);   // 0..255 = (row, half)
        int r    = unit >> 1;
        int hsel = unit & 1;
        int pg   = (tid & 7) ^ (r & 7);
        ushort8 u = *reinterpret_cast<const ushort8*>(
            &SMEM[r * 128 + (hsel * 8 + (tid & 7)) * 8]);
        int rg = r0 + r;
        int nb = rg & 3, l = rg >> 2;
        int cbase = c0 + hsel * 64;
        unsigned short* dstp;
        if (c0 < EMB) {
            dstp = &qws[((size_t)(nb * NH + (cbase >> 6)) * LSEQ + l) * DH];
        } else {
            int c2 = cbase - EMB;
            dstp = &kws[((size_t)(nb * NH + (c2 >> 6)) * LSEQ + l) * DH];
        }
        *reinterpret_cast<ushort8*>(dstp + pg * 8) = u;
    }
}

// ---- attn helpers ----
__device__ __forceinline__ void lds_kfrag(const unsigned short* Ks, int ti, int m, int half,
                                          bf16x8* kf) {
    const char* base = reinterpret_cast<const char*>(Ks);
    #pragma unroll
    for (int kk = 0; kk < 4; ++kk) {
        int byte = ti * 4096 + m * 128 + ((half * 16 + kk * 32) ^ ((m & 7) << 4));
        kf[kk] = *reinterpret_cast<const bf16x8*>(base + byte);
    }
}
__device__ __forceinline__ f32x16 mfma_tile(const bf16x8* kf, const bf16x8* qf) {
    f32x16 acc;
    #pragma unroll
    for (int j = 0; j < 16; ++j) acc[j] = NEG16LOG2E;
    #pragma unroll
    for (int kk = 0; kk < 4; ++kk)
        acc = __builtin_amdgcn_mfma_f32_32x32x16_bf16(kf[kk], qf[kk], acc, 0, 0, 0);
    return acc;
}
__device__ __forceinline__ void expacc(const f32x16& acc, const float* vt, int half,
                                       f32x2& z2, f32x2& o2) {
    #pragma unroll
    for (int q = 0; q < 4; ++q) {
        float4 v4 = *reinterpret_cast<const float4*>(&vt[8 * q + 4 * half]);
        f32x2 p01 = {EXP2F(acc[4 * q + 0]), EXP2F(acc[4 * q + 1])};
        f32x2 p23 = {EXP2F(acc[4 * q + 2]), EXP2F(acc[4 * q + 3])};
        f32x2 v01 = {v4.x, v4.y};
        f32x2 v23 = {v4.z, v4.w};
        z2 += p01;
        o2 += p01 * v01;
        z2 += p23;
        o2 += p23 * v23;
    }
}
__device__ __forceinline__ void expacc_diag(const f32x16& acc, const float* vt, int half,
                                            int row, f32x2& z2, f32x2& o2) {
    #pragma unroll
    for (int q = 0; q < 4; ++q) {
        float4 v4 = *reinterpret_cast<const float4*>(&vt[8 * q + 4 * half]);
        float vvq[4] = {v4.x, v4.y, v4.z, v4.w};
        #pragma unroll
        for (int j = 0; j < 4; ++j) {
            int mrow = j + 8 * q + 4 * half;
            float p = EXP2F(acc[4 * q + j]);
            p = (mrow <= row) ? p : 0.f;   // causal on diagonal tile
            z2[0] += p;
            o2[0] += p * vvq[j];
        }
    }
}

// ---- K-stationary MFMA causal attention (Q prefetched across l-blocks) ----
__global__ __launch_bounds__(512) void attn_mfma(const unsigned short* __restrict__ qws,
                                                 const unsigned short* __restrict__ kws,
                                                 const float* __restrict__ vw,
                                                 float2* __restrict__ zopart) {
    __shared__ unsigned short Ks[CCH * 2048];   // 8 tiles x 4KB = 32KB
    __shared__ float vt[CCH][32];               // vw values for owned tiles
    const int tid = threadIdx.x;
    const int b   = blockIdx.x & 63;            // low bits: all chunks of b on one XCD
    const int c   = blockIdx.x >> 6;

    {
        int ti = tid >> 6, lane = tid & 63;
        int row = lane >> 1, hb = lane & 1;
        const unsigned short* src = &kws[((size_t)b * LSEQ + (c + CCH * ti) * 32 + row) * DH + hb * 32];
        char* dst = reinterpret_cast<char*>(Ks) + ti * 4096 + row * 128;
        #pragma unroll
        for (int s = 0; s < 4; ++s) {
            ushort8 u = *reinterpret_cast<const ushort8*>(src + s * 8);
            *reinterpret_cast<ushort8*>(dst + ((hb * 64 + s * 16) ^ ((row & 7) << 4))) = u;
        }
        if (tid < 256) vt[tid >> 5][tid & 31] =
            vw[(size_t)b * LSEQ + (c + CCH * (tid >> 5)) * 32 + (tid & 31)];
    }
    __syncthreads();

    const int wid  = tid >> 6;
    const int lane = tid & 63;
    const int row  = lane & 31;
    const int half = lane >> 5;

    const unsigned short* qb_all = &qws[((size_t)b * LSEQ + row) * DH + 8 * half];
    bf16x8 qf[4], qn[4];
    #pragma unroll
    for (int kk = 0; kk < 4; ++kk)
        qf[kk] = *reinterpret_cast<const bf16x8*>(qb_all + (size_t)wid * 32 * DH + kk * 16);

    #pragma unroll
    for (int k = 0; k < 8; ++k) {
        const int lb = 8 * k + wid;
        if (k < 7) {
            const unsigned short* qnp = qb_all + (size_t)(lb + 8) * 32 * DH;
            #pragma unroll
            for (int kk = 0; kk < 4; ++kk)
                qn[kk] = *reinterpret_cast<const bf16x8*>(qnp + kk * 16);
        }
        const int nfull = (lb > c) ? ((lb - c + 7) >> 3) : 0;
        const bool has_diag = ((lb & 7) == c);
        f32x2 z2 = {0.f, 0.f}, o2 = {0.f, 0.f};
        if (nfull > 0 || has_diag) {
            int ti = 0;
            for (; ti + 1 < nfull; ti += 2) {   // ILP-2 over owned tiles
                bf16x8 ka[4], kc[4];
                lds_kfrag(Ks, ti, row, half, ka);
                lds_kfrag(Ks, ti + 1, row, half, kc);
                __builtin_amdgcn_s_setprio(1);
                f32x16 accA = mfma_tile(ka, qf);
                f32x16 accB = mfma_tile(kc, qf);
                __builtin_amdgcn_s_setprio(0);
                expacc(accA, &vt[ti][0], half, z2, o2);
                expacc(accB, &vt[ti + 1][0], half, z2, o2);
            }
            if (ti < nfull) {
                bf16x8 ka[4];
                lds_kfrag(Ks, ti, row, half, ka);
                f32x16 accA = mfma_tile(ka, qf);
                expacc(accA, &vt[ti][0], half, z2, o2);
            }
            if (has_diag) {
                const int td = nfull;
                bf16x8 ka[4];
                lds_kfrag(Ks, td, row, half, ka);
                f32x16 accA = mfma_tile(ka, qf);
                expacc_diag(accA, &vt[td][0], half, row, z2, o2);
            }
        }
        float z = z2[0] + z2[1];
        float o = o2[0] + o2[1];
        z += __shfl_xor(z, 32, 64);
        o += __shfl_xor(o, 32, 64);
        if (half == 0)
            zopart[((size_t)(b * 64 + lb) * CCH + c) * 32 + row] = float2{z, o};
        #pragma unroll
        for (int kk = 0; kk < 4; ++kk) qf[kk] = qn[kk];
    }
}

// ---- combine chunks: per (b,lb,col) -> o/z, block-reduce to 512 partials ----
__global__ __launch_bounds__(256) void attn_combine(const float2* __restrict__ zopart,
                                                    float* __restrict__ partials) {
    __shared__ float red[256];
    const int t = threadIdx.x;
    const int e = blockIdx.x * 256 + t;
    const int bl = e >> 5, col = e & 31;
    float z = 0.f, o = 0.f;
    #pragma unroll
    for (int c = 0; c < CCH; ++c) {
        float2 p = zopart[((size_t)bl * CCH + c) * 32 + col];
        z += p.x; o += p.y;
    }
    red[t] = o / z;
    __syncthreads();
    for (int sh = 128; sh > 0; sh >>= 1) {
        if (t < sh) red[t] += red[t + sh];
        __syncthreads();
    }
    if (t == 0) partials[blockIdx.x] = red[0];
}

// ---- final deterministic reduction of 512 partials ----
__global__ void reduce_kernel(const float* __restrict__ partials, float* __restrict__ out) {
    __shared__ float red[256];
    int t = threadIdx.x;
    red[t] = partials[t] + partials[t + 256];
    __syncthreads();
    for (int sh = 128; sh > 0; sh >>= 1) {
        if (t < sh) red[t] += red[t + sh];
        __syncthreads();
    }
    if (t == 0) out[0] = red[0];
}

extern "C" void kernel_launch(void* const* d_in, const int* in_sizes, int n_in,
                              void* d_out, int out_size, void* d_ws, size_t ws_size,
                              hipStream_t stream) {
    const float* x    = (const float*)d_in[0];
    const float* wqkv = (const float*)d_in[1];
    const float* wout = (const float*)d_in[2];
    float* out = (float*)d_out;

    unsigned short* qws = (unsigned short*)d_ws;
    unsigned short* kws = qws + (size_t)BH * LSEQ * DH;
    unsigned short* xb  = kws + (size_t)BH * LSEQ * DH;
    unsigned short* wb  = xb + (size_t)LSEQ * NB * EMB;
    float* vw       = (float*)(wb + (size_t)2 * EMB * EMB);
    float* wsum     = vw + (size_t)BH * LSEQ;
    float* wveff    = wsum + EMB;
    float* partials = wveff + NH * EMB;
    float* wpart    = partials + 1024;
    // zopart (8.4 MB) aliases xb (16 MB): proj_mfma (the only xb reader)
    // completes before attn_mfma writes; xb is rewritten every call (by vw).
    float2* zopart  = (float2*)xb;

    hipLaunchKernelGGL(prep_kernel,   dim3(1024 + 128), dim3(256), 0, stream,
                       wqkv, wout, wb, wpart);
    hipLaunchKernelGGL(wsum_final_kernel, dim3(EMB / 256), dim3(256), 0, stream, wpart, wsum);
    hipLaunchKernelGGL(wveff_kernel,  dim3(NH * EMB / 256), dim3(256), 0, stream, wqkv, wsum, wveff);
    hipLaunchKernelGGL(vw_kernel,     dim3(LSEQ * NB / 4), dim3(256), 0, stream, x, wveff, vw, xb);
    hipLaunchKernelGGL(proj_mfma,     dim3(1024), dim3(512), 0, stream,
                       xb, wb, qws, kws);
    hipLaunchKernelGGL(attn_mfma,     dim3(BH * CCH), dim3(512), 0, stream,
                       qws, kws, vw, zopart);
    hipLaunchKernelGGL(attn_combine,  dim3(512), dim3(256), 0, stream, zopart, partials);
    hipLaunchKernelGGL(reduce_kernel, dim3(1), dim3(256), 0, stream, partials, out);
}

// Round 21
// 117.511 us; speedup vs baseline: 1.2983x; 1.2983x over previous
//
#include <hip/hip_runtime.h>
#include <hip/hip_bf16.h>

#define LSEQ 2048
#define NB   4
#define EMB  1024
#define NH   16
#define DH   64
#define BH   (NB*NH)   // 64 head-batches
#define SCALE 0.125f   // d^-0.5
#define CCH  8         // K-tile chunks per b (block-level, stride-interleaved)
#define LOG2E 1.4426950408889634f
#define NEG16LOG2E (-23.083120654223414f)   // -16*log2e (acc C-init)

typedef unsigned short ushort8 __attribute__((ext_vector_type(8)));
typedef __attribute__((ext_vector_type(8))) short bf16x8;    // MFMA A/B frag (8 bf16)
typedef __attribute__((ext_vector_type(4))) float f32x4;     // 16x16 C/D frag
typedef __attribute__((ext_vector_type(16))) float f32x16;   // 32x32 C/D frag
typedef __attribute__((ext_vector_type(2))) float f32x2;     // packed z/o acc

#define EXP2F(x) __builtin_amdgcn_exp2f(x)   // v_exp_f32 (HW exp2)

__device__ __forceinline__ unsigned short f_to_bf(float f) {
    unsigned int u = __float_as_uint(f);
    return (unsigned short)((u + 0x7fffu + ((u >> 16) & 1u)) >> 16);
}

__device__ __forceinline__ void gload_lds16(const void* g, void* l) {
    __builtin_amdgcn_global_load_lds(
        (const __attribute__((address_space(1))) unsigned int*)g,
        (__attribute__((address_space(3))) unsigned int*)l, 16, 0, 0);
}

// ---- prep: fused tobf16(wqkv) [blocks 0..1023] + wsum_part [1024..1151] ----
__global__ __launch_bounds__(256) void prep_kernel(const float* __restrict__ wqkv,
                                                   const float* __restrict__ wout,
                                                   unsigned short* __restrict__ wb,
                                                   float* __restrict__ wpart) {
    if (blockIdx.x < 1024) {
        int i = blockIdx.x * 256 + threadIdx.x;   // < 2*EMB*EMB/8
        const float4* p = reinterpret_cast<const float4*>(wqkv) + (size_t)i * 2;
        float4 a = p[0], b = p[1];
        ushort8 o;
        o[0] = f_to_bf(a.x); o[1] = f_to_bf(a.y); o[2] = f_to_bf(a.z); o[3] = f_to_bf(a.w);
        o[4] = f_to_bf(b.x); o[5] = f_to_bf(b.y); o[6] = f_to_bf(b.z); o[7] = f_to_bf(b.w);
        reinterpret_cast<ushort8*>(wb)[i] = o;
    } else {
        int bb = blockIdx.x - 1024;
        int fc = bb >> 2;
        int e  = (bb & 3) * 256 + threadIdx.x;
        float s = 0.f;
        #pragma unroll 8
        for (int f = fc * 32; f < fc * 32 + 32; ++f) s += wout[(size_t)f * EMB + e];
        wpart[(size_t)fc * EMB + e] = s;
    }
}

__global__ __launch_bounds__(256) void wsum_final_kernel(const float* __restrict__ wpart,
                                                         float* __restrict__ wsum) {
    int e = blockIdx.x * 256 + threadIdx.x;
    float s = 0.f;
    #pragma unroll
    for (int c = 0; c < 32; ++c) s += wpart[(size_t)c * EMB + e];
    wsum[e] = s;
}

// ---- wv_eff[h][e] = sum_j wqkv[2E + h*64 + j][e] * wsum[h*64+j] ----
__global__ void wveff_kernel(const float* __restrict__ wqkv, const float* __restrict__ wsum,
                             float* __restrict__ wveff) {
    int idx = blockIdx.x * 256 + threadIdx.x;   // h*EMB + e
    int h = idx >> 10, e = idx & 1023;
    float s = 0.f;
    #pragma unroll 8
    for (int j = 0; j < DH; ++j)
        s += wqkv[(size_t)(2 * EMB + h * DH + j) * EMB + e] * wsum[h * DH + j];
    wveff[idx] = s;
}

// ---- vw[b][m] = sum_e x[m,n,e]*wveff[h,e] + fused x->bf16 (R18-exact:
// stride-64 scalar loads keep VGPR low; float4 variant blew VGPR to 140, 2x slower) ----
__global__ __launch_bounds__(256) void vw_kernel(const float* __restrict__ x,
                                                 const float* __restrict__ wveff,
                                                 float* __restrict__ vw,
                                                 unsigned short* __restrict__ xb) {
    int wave = threadIdx.x >> 6;
    int lane = threadIdx.x & 63;
    int r = blockIdx.x * 4 + wave;   // r = l*NB + n
    int n = r & 3, l = r >> 2;
    float acc[NH] = {};
    for (int e = lane; e < EMB; e += 64) {
        float xe = x[(size_t)r * EMB + e];
        xb[(size_t)r * EMB + e] = f_to_bf(xe);
        #pragma unroll
        for (int h = 0; h < NH; ++h) acc[h] += xe * wveff[h * EMB + e];
    }
    #pragma unroll
    for (int h = 0; h < NH; ++h) {
        float v = acc[h];
        #pragma unroll
        for (int off = 32; off > 0; off >>= 1) v += __shfl_down(v, off, 64);
        if (lane == 0) vw[(size_t)(n * NH + h) * LSEQ + l] = v;
    }
}

// ---- bf16 MFMA Q/K projection: PBK=64 dbuf, 8 waves (R18-exact) ----
#define PBM 128
#define PBN 128
#define PBK 64
#define BUFS ((PBM + PBN) * PBK)   // shorts per buffer (32 KB)

__device__ __forceinline__ void proj_stage(const unsigned short* __restrict__ xb,
                                           const unsigned short* __restrict__ wb,
                                           unsigned short* As, unsigned short* Bs,
                                           int r0, int c0, int k0, int wid, int srow, int sj) {
    #pragma unroll
    for (int i = 0; i < 2; ++i) {
        int seg = wid * 2 + i;                    // 16 segments of 8 rows
        gload_lds16(&xb[(size_t)(r0 + seg * 8 + srow) * EMB + k0 + sj], &As[seg * 8 * PBK]);
        gload_lds16(&wb[(size_t)(c0 + seg * 8 + srow) * EMB + k0 + sj], &Bs[seg * 8 * PBK]);
    }
}

__device__ __forceinline__ void proj_compute(const unsigned short* As, const unsigned short* Bs,
                                             int wr, int wc, int col, int g, f32x4 (&acc)[4][2]) {
    #pragma unroll
    for (int kk = 0; kk < 2; ++kk) {
        bf16x8 af[4], bff[2];
        #pragma unroll
        for (int m = 0; m < 4; ++m) {
            int row = wr * 64 + m * 16 + col;
            af[m] = *reinterpret_cast<const bf16x8*>(
                &As[row * PBK + (((kk * 4 + g) ^ (row & 7)) * 8)]);
        }
        #pragma unroll
        for (int n = 0; n < 2; ++n) {
            int row = wc * 32 + n * 16 + col;
            bff[n] = *reinterpret_cast<const bf16x8*>(
                &Bs[row * PBK + (((kk * 4 + g) ^ (row & 7)) * 8)]);
        }
        #pragma unroll
        for (int m = 0; m < 4; ++m)
            #pragma unroll
            for (int n = 0; n < 2; ++n)
                acc[m][n] = __builtin_amdgcn_mfma_f32_16x16x32_bf16(af[m], bff[n], acc[m][n], 0, 0, 0);
    }
}

__global__ __launch_bounds__(512) void proj_mfma(const unsigned short* __restrict__ xb,
                                                 const unsigned short* __restrict__ wb,
                                                 unsigned short* __restrict__ qws,
                                                 unsigned short* __restrict__ kws) {
    __shared__ unsigned short SMEM[2 * BUFS];   // 64 KB (dbuf)
    unsigned short* As0 = SMEM;
    unsigned short* Bs0 = SMEM + PBM * PBK;
    unsigned short* As1 = SMEM + BUFS;
    unsigned short* Bs1 = As1 + PBM * PBK;
    const int tid  = threadIdx.x;
    const int lane = tid & 63;
    const int wid  = tid >> 6;                 // 0..7
    const int wr   = wid >> 2, wc = wid & 3;   // 2x4 wave grid, wave tile 64x32
    const int d  = blockIdx.x;
    const int w  = (d & 7) * 128 + (d >> 3);
    const int r0 = (w >> 4) * PBM;
    const int c0 = (w & 15) * PBN;
    const int col  = lane & 15, g = lane >> 4;

    f32x4 acc[4][2];
    #pragma unroll
    for (int m = 0; m < 4; ++m)
        #pragma unroll
        for (int n = 0; n < 2; ++n) acc[m][n] = f32x4{0.f, 0.f, 0.f, 0.f};

    const int srow = lane >> 3;
    const int sj   = ((lane & 7) ^ (lane >> 3)) * 8;

    proj_stage(xb, wb, As0, Bs0, r0, c0, 0, wid, srow, sj);
    __syncthreads();
    #pragma unroll 1
    for (int t = 0; t < 16; t += 2) {
        proj_stage(xb, wb, As1, Bs1, r0, c0, (t + 1) * PBK, wid, srow, sj);
        proj_compute(As0, Bs0, wr, wc, col, g, acc);
        __syncthreads();
        if (t + 2 < 16)
            proj_stage(xb, wb, As0, Bs0, r0, c0, (t + 2) * PBK, wid, srow, sj);
        proj_compute(As1, Bs1, wr, wc, col, g, acc);
        __syncthreads();
    }

    const float scl = (c0 < EMB) ? SCALE * LOG2E : 1.0f;   // block is purely Q or K
    #pragma unroll
    for (int m = 0; m < 4; ++m) {
        #pragma unroll
        for (int n = 0; n < 2; ++n) {
            #pragma unroll
            for (int j = 0; j < 4; ++j) {
                int row = wr * 64 + m * 16 + g * 4 + j;
                int cc  = wc * 32 + n * 16 + col;
                SMEM[row * 128 + (((cc >> 3) ^ (row & 7)) * 8) + (cc & 7)] =
                    f_to_bf(acc[m][n][j] * scl);
            }
        }
    }
    __syncthreads();
    #pragma unroll
    for (int pass = 0; pass < 4; ++pass) {
        int unit = pass * 64 + (tid >> 3);   // 0..255 = (row, half)
        int r    = unit >> 1;
        int hsel = unit & 1;
        int pg   = (tid & 7) ^ (r & 7);
        ushort8 u = *reinterpret_cast<const ushort8*>(
            &SMEM[r * 128 + (hsel * 8 + (tid & 7)) * 8]);
        int rg = r0 + r;
        int nb = rg & 3, l = rg >> 2;
        int cbase = c0 + hsel * 64;
        unsigned short* dstp;
        if (c0 < EMB) {
            dstp = &qws[((size_t)(nb * NH + (cbase >> 6)) * LSEQ + l) * DH];
        } else {
            int c2 = cbase - EMB;
            dstp = &kws[((size_t)(nb * NH + (c2 >> 6)) * LSEQ + l) * DH];
        }
        *reinterpret_cast<ushort8*>(dstp + pg * 8) = u;
    }
}

// ---- attn helpers ----
__device__ __forceinline__ void lds_kfrag(const unsigned short* Ks, int ti, int m, int half,
                                          bf16x8* kf) {
    const char* base = reinterpret_cast<const char*>(Ks);
    #pragma unroll
    for (int kk = 0; kk < 4; ++kk) {
        int byte = ti * 4096 + m * 128 + ((half * 16 + kk * 32) ^ ((m & 7) << 4));
        kf[kk] = *reinterpret_cast<const bf16x8*>(base + byte);
    }
}
__device__ __forceinline__ f32x16 mfma_tile(const bf16x8* kf, const bf16x8* qf) {
    f32x16 acc;
    #pragma unroll
    for (int j = 0; j < 16; ++j) acc[j] = NEG16LOG2E;
    #pragma unroll
    for (int kk = 0; kk < 4; ++kk)
        acc = __builtin_amdgcn_mfma_f32_32x32x16_bf16(kf[kk], qf[kk], acc, 0, 0, 0);
    return acc;
}
__device__ __forceinline__ void expacc(const f32x16& acc, const float* vt, int half,
                                       f32x2& z2, f32x2& o2) {
    #pragma unroll
    for (int q = 0; q < 4; ++q) {
        float4 v4 = *reinterpret_cast<const float4*>(&vt[8 * q + 4 * half]);
        f32x2 p01 = {EXP2F(acc[4 * q + 0]), EXP2F(acc[4 * q + 1])};
        f32x2 p23 = {EXP2F(acc[4 * q + 2]), EXP2F(acc[4 * q + 3])};
        f32x2 v01 = {v4.x, v4.y};
        f32x2 v23 = {v4.z, v4.w};
        z2 += p01;
        o2 += p01 * v01;
        z2 += p23;
        o2 += p23 * v23;
    }
}
__device__ __forceinline__ void expacc_diag(const f32x16& acc, const float* vt, int half,
                                            int row, f32x2& z2, f32x2& o2) {
    #pragma unroll
    for (int q = 0; q < 4; ++q) {
        float4 v4 = *reinterpret_cast<const float4*>(&vt[8 * q + 4 * half]);
        float vvq[4] = {v4.x, v4.y, v4.z, v4.w};
        #pragma unroll
        for (int j = 0; j < 4; ++j) {
            int mrow = j + 8 * q + 4 * half;
            float p = EXP2F(acc[4 * q + j]);
            p = (mrow <= row) ? p : 0.f;   // causal on diagonal tile
            z2[0] += p;
            o2[0] += p * vvq[j];
        }
    }
}

// ---- K-stationary MFMA causal attention (Q prefetched across l-blocks) ----
__global__ __launch_bounds__(512) void attn_mfma(const unsigned short* __restrict__ qws,
                                                 const unsigned short* __restrict__ kws,
                                                 const float* __restrict__ vw,
                                                 float2* __restrict__ zopart) {
    __shared__ unsigned short Ks[CCH * 2048];   // 8 tiles x 4KB = 32KB
    __shared__ float vt[CCH][32];               // vw values for owned tiles
    const int tid = threadIdx.x;
    const int b   = blockIdx.x & 63;            // low bits: all chunks of b on one XCD
    const int c   = blockIdx.x >> 6;

    {
        int ti = tid >> 6, lane = tid & 63;
        int row = lane >> 1, hb = lane & 1;
        const unsigned short* src = &kws[((size_t)b * LSEQ + (c + CCH * ti) * 32 + row) * DH + hb * 32];
        char* dst = reinterpret_cast<char*>(Ks) + ti * 4096 + row * 128;
        #pragma unroll
        for (int s = 0; s < 4; ++s) {
            ushort8 u = *reinterpret_cast<const ushort8*>(src + s * 8);
            *reinterpret_cast<ushort8*>(dst + ((hb * 64 + s * 16) ^ ((row & 7) << 4))) = u;
        }
        if (tid < 256) vt[tid >> 5][tid & 31] =
            vw[(size_t)b * LSEQ + (c + CCH * (tid >> 5)) * 32 + (tid & 31)];
    }
    __syncthreads();

    const int wid  = tid >> 6;
    const int lane = tid & 63;
    const int row  = lane & 31;
    const int half = lane >> 5;

    const unsigned short* qb_all = &qws[((size_t)b * LSEQ + row) * DH + 8 * half];
    bf16x8 qf[4], qn[4];
    #pragma unroll
    for (int kk = 0; kk < 4; ++kk)
        qf[kk] = *reinterpret_cast<const bf16x8*>(qb_all + (size_t)wid * 32 * DH + kk * 16);

    #pragma unroll
    for (int k = 0; k < 8; ++k) {
        const int lb = 8 * k + wid;
        if (k < 7) {
            const unsigned short* qnp = qb_all + (size_t)(lb + 8) * 32 * DH;
            #pragma unroll
            for (int kk = 0; kk < 4; ++kk)
                qn[kk] = *reinterpret_cast<const bf16x8*>(qnp + kk * 16);
        }
        const int nfull = (lb > c) ? ((lb - c + 7) >> 3) : 0;
        const bool has_diag = ((lb & 7) == c);
        f32x2 z2 = {0.f, 0.f}, o2 = {0.f, 0.f};
        if (nfull > 0 || has_diag) {
            int ti = 0;
            for (; ti + 1 < nfull; ti += 2) {   // ILP-2 over owned tiles
                bf16x8 ka[4], kc[4];
                lds_kfrag(Ks, ti, row, half, ka);
                lds_kfrag(Ks, ti + 1, row, half, kc);
                __builtin_amdgcn_s_setprio(1);
                f32x16 accA = mfma_tile(ka, qf);
                f32x16 accB = mfma_tile(kc, qf);
                __builtin_amdgcn_s_setprio(0);
                expacc(accA, &vt[ti][0], half, z2, o2);
                expacc(accB, &vt[ti + 1][0], half, z2, o2);
            }
            if (ti < nfull) {
                bf16x8 ka[4];
                lds_kfrag(Ks, ti, row, half, ka);
                f32x16 accA = mfma_tile(ka, qf);
                expacc(accA, &vt[ti][0], half, z2, o2);
            }
            if (has_diag) {
                const int td = nfull;
                bf16x8 ka[4];
                lds_kfrag(Ks, td, row, half, ka);
                f32x16 accA = mfma_tile(ka, qf);
                expacc_diag(accA, &vt[td][0], half, row, z2, o2);
            }
        }
        float z = z2[0] + z2[1];
        float o = o2[0] + o2[1];
        z += __shfl_xor(z, 32, 64);
        o += __shfl_xor(o, 32, 64);
        if (half == 0)
            zopart[((size_t)(b * 64 + lb) * CCH + c) * 32 + row] = float2{z, o};
        #pragma unroll
        for (int kk = 0; kk < 4; ++kk) qf[kk] = qn[kk];
    }
}

// ---- combine chunks: per (b,lb,col) -> o/z, block-reduce to 512 partials ----
__global__ __launch_bounds__(256) void attn_combine(const float2* __restrict__ zopart,
                                                    float* __restrict__ partials) {
    __shared__ float red[256];
    const int t = threadIdx.x;
    const int e = blockIdx.x * 256 + t;
    const int bl = e >> 5, col = e & 31;
    float z = 0.f, o = 0.f;
    #pragma unroll
    for (int c = 0; c < CCH; ++c) {
        float2 p = zopart[((size_t)bl * CCH + c) * 32 + col];
        z += p.x; o += p.y;
    }
    red[t] = o / z;
    __syncthreads();
    for (int sh = 128; sh > 0; sh >>= 1) {
        if (t < sh) red[t] += red[t + sh];
        __syncthreads();
    }
    if (t == 0) partials[blockIdx.x] = red[0];
}

// ---- final deterministic reduction of 512 partials ----
__global__ void reduce_kernel(const float* __restrict__ partials, float* __restrict__ out) {
    __shared__ float red[256];
    int t = threadIdx.x;
    red[t] = partials[t] + partials[t + 256];
    __syncthreads();
    for (int sh = 128; sh > 0; sh >>= 1) {
        if (t < sh) red[t] += red[t + sh];
        __syncthreads();
    }
    if (t == 0) out[0] = red[0];
}

extern "C" void kernel_launch(void* const* d_in, const int* in_sizes, int n_in,
                              void* d_out, int out_size, void* d_ws, size_t ws_size,
                              hipStream_t stream) {
    const float* x    = (const float*)d_in[0];
    const float* wqkv = (const float*)d_in[1];
    const float* wout = (const float*)d_in[2];
    float* out = (float*)d_out;

    unsigned short* qws = (unsigned short*)d_ws;
    unsigned short* kws = qws + (size_t)BH * LSEQ * DH;
    unsigned short* xb  = kws + (size_t)BH * LSEQ * DH;
    unsigned short* wb  = xb + (size_t)LSEQ * NB * EMB;
    float* vw       = (float*)(wb + (size_t)2 * EMB * EMB);
    float* wsum     = vw + (size_t)BH * LSEQ;
    float* wveff    = wsum + EMB;
    float* partials = wveff + NH * EMB;
    float* wpart    = partials + 1024;
    // zopart (8.4 MB) aliases xb (16 MB): proj_mfma (the only xb reader)
    // completes before attn_mfma writes; xb is rewritten every call (by vw).
    float2* zopart  = (float2*)xb;

    hipLaunchKernelGGL(prep_kernel,   dim3(1024 + 128), dim3(256), 0, stream,
                       wqkv, wout, wb, wpart);
    hipLaunchKernelGGL(wsum_final_kernel, dim3(EMB / 256), dim3(256), 0, stream, wpart, wsum);
    hipLaunchKernelGGL(wveff_kernel,  dim3(NH * EMB / 256), dim3(256), 0, stream, wqkv, wsum, wveff);
    hipLaunchKernelGGL(vw_kernel,     dim3(LSEQ * NB / 4), dim3(256), 0, stream, x, wveff, vw, xb);
    hipLaunchKernelGGL(proj_mfma,     dim3(1024), dim3(512), 0, stream,
                       xb, wb, qws, kws);
    hipLaunchKernelGGL(attn_mfma,     dim3(BH * CCH), dim3(512), 0, stream,
                       qws, kws, vw, zopart);
    hipLaunchKernelGGL(attn_combine,  dim3(512), dim3(256), 0, stream, zopart, partials);
    hipLaunchKernelGGL(reduce_kernel, dim3(1), dim3(256), 0, stream, partials, out);
}

// Round 22
// 117.174 us; speedup vs baseline: 1.3020x; 1.0029x over previous
//
#include <hip/hip_runtime.h>
#include <hip/hip_bf16.h>

#define LSEQ 2048
#define NB   4
#define EMB  1024
#define NH   16
#define DH   64
#define BH   (NB*NH)   // 64 head-batches
#define SCALE 0.125f   // d^-0.5
#define CCH  8         // K-tile chunks per b (block-level, stride-interleaved)
#define LOG2E 1.4426950408889634f
#define NEG16LOG2E (-23.083120654223414f)   // -16*log2e (acc C-init)

typedef unsigned short ushort8 __attribute__((ext_vector_type(8)));
typedef __attribute__((ext_vector_type(8))) short bf16x8;    // MFMA A/B frag (8 bf16)
typedef __attribute__((ext_vector_type(4))) float f32x4;     // 16x16 C/D frag
typedef __attribute__((ext_vector_type(16))) float f32x16;   // 32x32 C/D frag
typedef __attribute__((ext_vector_type(2))) float f32x2;     // packed z/o acc

#define EXP2F(x) __builtin_amdgcn_exp2f(x)   // v_exp_f32 (HW exp2)

// counted-vmcnt barrier primitives (raw s_barrier: no compiler vmcnt(0) drain)
#define WAITV4  asm volatile("s_waitcnt vmcnt(4)" ::: "memory")
#define WAITV0  asm volatile("s_waitcnt vmcnt(0)" ::: "memory")
#define RBAR    asm volatile("s_barrier" ::: "memory")

__device__ __forceinline__ unsigned short f_to_bf(float f) {
    unsigned int u = __float_as_uint(f);
    return (unsigned short)((u + 0x7fffu + ((u >> 16) & 1u)) >> 16);
}

__device__ __forceinline__ void gload_lds16(const void* g, void* l) {
    __builtin_amdgcn_global_load_lds(
        (const __attribute__((address_space(1))) unsigned int*)g,
        (__attribute__((address_space(3))) unsigned int*)l, 16, 0, 0);
}

// ---- prep: fused tobf16(wqkv) [blocks 0..1023] + wsum_part [1024..1151] ----
__global__ __launch_bounds__(256) void prep_kernel(const float* __restrict__ wqkv,
                                                   const float* __restrict__ wout,
                                                   unsigned short* __restrict__ wb,
                                                   float* __restrict__ wpart) {
    if (blockIdx.x < 1024) {
        int i = blockIdx.x * 256 + threadIdx.x;   // < 2*EMB*EMB/8
        const float4* p = reinterpret_cast<const float4*>(wqkv) + (size_t)i * 2;
        float4 a = p[0], b = p[1];
        ushort8 o;
        o[0] = f_to_bf(a.x); o[1] = f_to_bf(a.y); o[2] = f_to_bf(a.z); o[3] = f_to_bf(a.w);
        o[4] = f_to_bf(b.x); o[5] = f_to_bf(b.y); o[6] = f_to_bf(b.z); o[7] = f_to_bf(b.w);
        reinterpret_cast<ushort8*>(wb)[i] = o;
    } else {
        int bb = blockIdx.x - 1024;
        int fc = bb >> 2;
        int e  = (bb & 3) * 256 + threadIdx.x;
        float s = 0.f;
        #pragma unroll 8
        for (int f = fc * 32; f < fc * 32 + 32; ++f) s += wout[(size_t)f * EMB + e];
        wpart[(size_t)fc * EMB + e] = s;
    }
}

__global__ __launch_bounds__(256) void wsum_final_kernel(const float* __restrict__ wpart,
                                                         float* __restrict__ wsum) {
    int e = blockIdx.x * 256 + threadIdx.x;
    float s = 0.f;
    #pragma unroll
    for (int c = 0; c < 32; ++c) s += wpart[(size_t)c * EMB + e];
    wsum[e] = s;
}

// ---- wv_eff[h][e] = sum_j wqkv[2E + h*64 + j][e] * wsum[h*64+j] ----
__global__ void wveff_kernel(const float* __restrict__ wqkv, const float* __restrict__ wsum,
                             float* __restrict__ wveff) {
    int idx = blockIdx.x * 256 + threadIdx.x;   // h*EMB + e
    int h = idx >> 10, e = idx & 1023;
    float s = 0.f;
    #pragma unroll 8
    for (int j = 0; j < DH; ++j)
        s += wqkv[(size_t)(2 * EMB + h * DH + j) * EMB + e] * wsum[h * DH + j];
    wveff[idx] = s;
}

// ---- vw[b][m] = sum_e x[m,n,e]*wveff[h,e] + fused x->bf16 (R18-exact:
// stride-64 scalar loads keep VGPR low; float4 variant blew VGPR to 140, 2x slower) ----
__global__ __launch_bounds__(256) void vw_kernel(const float* __restrict__ x,
                                                 const float* __restrict__ wveff,
                                                 float* __restrict__ vw,
                                                 unsigned short* __restrict__ xb) {
    int wave = threadIdx.x >> 6;
    int lane = threadIdx.x & 63;
    int r = blockIdx.x * 4 + wave;   // r = l*NB + n
    int n = r & 3, l = r >> 2;
    float acc[NH] = {};
    for (int e = lane; e < EMB; e += 64) {
        float xe = x[(size_t)r * EMB + e];
        xb[(size_t)r * EMB + e] = f_to_bf(xe);
        #pragma unroll
        for (int h = 0; h < NH; ++h) acc[h] += xe * wveff[h * EMB + e];
    }
    #pragma unroll
    for (int h = 0; h < NH; ++h) {
        float v = acc[h];
        #pragma unroll
        for (int off = 32; off > 0; off >>= 1) v += __shfl_down(v, off, 64);
        if (lane == 0) vw[(size_t)(n * NH + h) * LSEQ + l] = v;
    }
}

// ---- bf16 MFMA Q/K projection: PBK=64 dbuf, 8 waves, COUNTED-VMCNT pipeline ----
// Raw s_barrier + vmcnt(4): next tile's 4 gload_lds stay in flight across the
// barrier; only the previous tile's loads (a full compute phase old) are waited.
#define PBM 128
#define PBN 128
#define PBK 64
#define BUFS ((PBM + PBN) * PBK)   // shorts per buffer (32 KB)

__device__ __forceinline__ void proj_stage(const unsigned short* __restrict__ xb,
                                           const unsigned short* __restrict__ wb,
                                           unsigned short* As, unsigned short* Bs,
                                           int r0, int c0, int k0, int wid, int srow, int sj) {
    #pragma unroll
    for (int i = 0; i < 2; ++i) {
        int seg = wid * 2 + i;                    // 16 segments of 8 rows
        gload_lds16(&xb[(size_t)(r0 + seg * 8 + srow) * EMB + k0 + sj], &As[seg * 8 * PBK]);
        gload_lds16(&wb[(size_t)(c0 + seg * 8 + srow) * EMB + k0 + sj], &Bs[seg * 8 * PBK]);
    }
}

__device__ __forceinline__ void proj_compute(const unsigned short* As, const unsigned short* Bs,
                                             int wr, int wc, int col, int g, f32x4 (&acc)[4][2]) {
    #pragma unroll
    for (int kk = 0; kk < 2; ++kk) {
        bf16x8 af[4], bff[2];
        #pragma unroll
        for (int m = 0; m < 4; ++m) {
            int row = wr * 64 + m * 16 + col;
            af[m] = *reinterpret_cast<const bf16x8*>(
                &As[row * PBK + (((kk * 4 + g) ^ (row & 7)) * 8)]);
        }
        #pragma unroll
        for (int n = 0; n < 2; ++n) {
            int row = wc * 32 + n * 16 + col;
            bff[n] = *reinterpret_cast<const bf16x8*>(
                &Bs[row * PBK + (((kk * 4 + g) ^ (row & 7)) * 8)]);
        }
        #pragma unroll
        for (int m = 0; m < 4; ++m)
            #pragma unroll
            for (int n = 0; n < 2; ++n)
                acc[m][n] = __builtin_amdgcn_mfma_f32_16x16x32_bf16(af[m], bff[n], acc[m][n], 0, 0, 0);
    }
}

__global__ __launch_bounds__(512) void proj_mfma(const unsigned short* __restrict__ xb,
                                                 const unsigned short* __restrict__ wb,
                                                 unsigned short* __restrict__ qws,
                                                 unsigned short* __restrict__ kws) {
    __shared__ unsigned short SMEM[2 * BUFS];   // 64 KB (dbuf)
    unsigned short* As0 = SMEM;
    unsigned short* Bs0 = SMEM + PBM * PBK;
    unsigned short* As1 = SMEM + BUFS;
    unsigned short* Bs1 = As1 + PBM * PBK;
    const int tid  = threadIdx.x;
    const int lane = tid & 63;
    const int wid  = tid >> 6;                 // 0..7
    const int wr   = wid >> 2, wc = wid & 3;   // 2x4 wave grid, wave tile 64x32
    const int d  = blockIdx.x;
    const int w  = (d & 7) * 128 + (d >> 3);
    const int r0 = (w >> 4) * PBM;
    const int c0 = (w & 15) * PBN;
    const int col  = lane & 15, g = lane >> 4;

    f32x4 acc[4][2];
    #pragma unroll
    for (int m = 0; m < 4; ++m)
        #pragma unroll
        for (int n = 0; n < 2; ++n) acc[m][n] = f32x4{0.f, 0.f, 0.f, 0.f};

    const int srow = lane >> 3;
    const int sj   = ((lane & 7) ^ (lane >> 3)) * 8;

    proj_stage(xb, wb, As0, Bs0, r0, c0, 0, wid, srow, sj);
    WAITV0; RBAR;
    #pragma unroll 1
    for (int t = 0; t < 16; t += 2) {
        proj_stage(xb, wb, As1, Bs1, r0, c0, (t + 1) * PBK, wid, srow, sj);
        WAITV4; RBAR;                 // buf0 ready; buf1's 4 loads stay in flight
        proj_compute(As0, Bs0, wr, wc, col, g, acc);
        RBAR;                         // WAR: all buf0 reads done before re-stage
        if (t + 2 < 16) {
            proj_stage(xb, wb, As0, Bs0, r0, c0, (t + 2) * PBK, wid, srow, sj);
            WAITV4;
        } else {
            WAITV0;                   // tail: nothing in flight behind buf1
        }
        RBAR;
        proj_compute(As1, Bs1, wr, wc, col, g, acc);
        RBAR;
    }

    const float scl = (c0 < EMB) ? SCALE * LOG2E : 1.0f;   // block is purely Q or K
    #pragma unroll
    for (int m = 0; m < 4; ++m) {
        #pragma unroll
        for (int n = 0; n < 2; ++n) {
            #pragma unroll
            for (int j = 0; j < 4; ++j) {
                int row = wr * 64 + m * 16 + g * 4 + j;
                int cc  = wc * 32 + n * 16 + col;
                SMEM[row * 128 + (((cc >> 3) ^ (row & 7)) * 8) + (cc & 7)] =
                    f_to_bf(acc[m][n][j] * scl);
            }
        }
    }
    __syncthreads();
    #pragma unroll
    for (int pass = 0; pass < 4; ++pass) {
        int unit = pass * 64 + (tid >> 3);   // 0..255 = (row, half)
        int r    = unit >> 1;
        int hsel = unit & 1;
        int pg   = (tid & 7) ^ (r & 7);
        ushort8 u = *reinterpret_cast<const ushort8*>(
            &SMEM[r * 128 + (hsel * 8 + (tid & 7)) * 8]);
        int rg = r0 + r;
        int nb = rg & 3, l = rg >> 2;
        int cbase = c0 + hsel * 64;
        unsigned short* dstp;
        if (c0 < EMB) {
            dstp = &qws[((size_t)(nb * NH + (cbase >> 6)) * LSEQ + l) * DH];
        } else {
            int c2 = cbase - EMB;
            dstp = &kws[((size_t)(nb * NH + (c2 >> 6)) * LSEQ + l) * DH];
        }
        *reinterpret_cast<ushort8*>(dstp + pg * 8) = u;
    }
}

// ---- attn helpers ----
__device__ __forceinline__ void lds_kfrag(const unsigned short* Ks, int ti, int m, int half,
                                          bf16x8* kf) {
    const char* base = reinterpret_cast<const char*>(Ks);
    #pragma unroll
    for (int kk = 0; kk < 4; ++kk) {
        int byte = ti * 4096 + m * 128 + ((half * 16 + kk * 32) ^ ((m & 7) << 4));
        kf[kk] = *reinterpret_cast<const bf16x8*>(base + byte);
    }
}
__device__ __forceinline__ f32x16 mfma_tile(const bf16x8* kf, const bf16x8* qf) {
    f32x16 acc;
    #pragma unroll
    for (int j = 0; j < 16; ++j) acc[j] = NEG16LOG2E;
    #pragma unroll
    for (int kk = 0; kk < 4; ++kk)
        acc = __builtin_amdgcn_mfma_f32_32x32x16_bf16(kf[kk], qf[kk], acc, 0, 0, 0);
    return acc;
}
__device__ __forceinline__ void expacc(const f32x16& acc, const float* vt, int half,
                                       f32x2& z2, f32x2& o2) {
    #pragma unroll
    for (int q = 0; q < 4; ++q) {
        float4 v4 = *reinterpret_cast<const float4*>(&vt[8 * q + 4 * half]);
        f32x2 p01 = {EXP2F(acc[4 * q + 0]), EXP2F(acc[4 * q + 1])};
        f32x2 p23 = {EXP2F(acc[4 * q + 2]), EXP2F(acc[4 * q + 3])};
        f32x2 v01 = {v4.x, v4.y};
        f32x2 v23 = {v4.z, v4.w};
        z2 += p01;
        o2 += p01 * v01;
        z2 += p23;
        o2 += p23 * v23;
    }
}
__device__ __forceinline__ void expacc_diag(const f32x16& acc, const float* vt, int half,
                                            int row, f32x2& z2, f32x2& o2) {
    #pragma unroll
    for (int q = 0; q < 4; ++q) {
        float4 v4 = *reinterpret_cast<const float4*>(&vt[8 * q + 4 * half]);
        float vvq[4] = {v4.x, v4.y, v4.z, v4.w};
        #pragma unroll
        for (int j = 0; j < 4; ++j) {
            int mrow = j + 8 * q + 4 * half;
            float p = EXP2F(acc[4 * q + j]);
            p = (mrow <= row) ? p : 0.f;   // causal on diagonal tile
            z2[0] += p;
            o2[0] += p * vvq[j];
        }
    }
}

// ---- K-stationary MFMA causal attention (Q prefetched across l-blocks) ----
__global__ __launch_bounds__(512) void attn_mfma(const unsigned short* __restrict__ qws,
                                                 const unsigned short* __restrict__ kws,
                                                 const float* __restrict__ vw,
                                                 float2* __restrict__ zopart) {
    __shared__ unsigned short Ks[CCH * 2048];   // 8 tiles x 4KB = 32KB
    __shared__ float vt[CCH][32];               // vw values for owned tiles
    const int tid = threadIdx.x;
    const int b   = blockIdx.x & 63;            // low bits: all chunks of b on one XCD
    const int c   = blockIdx.x >> 6;

    {
        int ti = tid >> 6, lane = tid & 63;
        int row = lane >> 1, hb = lane & 1;
        const unsigned short* src = &kws[((size_t)b * LSEQ + (c + CCH * ti) * 32 + row) * DH + hb * 32];
        char* dst = reinterpret_cast<char*>(Ks) + ti * 4096 + row * 128;
        #pragma unroll
        for (int s = 0; s < 4; ++s) {
            ushort8 u = *reinterpret_cast<const ushort8*>(src + s * 8);
            *reinterpret_cast<ushort8*>(dst + ((hb * 64 + s * 16) ^ ((row & 7) << 4))) = u;
        }
        if (tid < 256) vt[tid >> 5][tid & 31] =
            vw[(size_t)b * LSEQ + (c + CCH * (tid >> 5)) * 32 + (tid & 31)];
    }
    __syncthreads();

    const int wid  = tid >> 6;
    const int lane = tid & 63;
    const int row  = lane & 31;
    const int half = lane >> 5;

    const unsigned short* qb_all = &qws[((size_t)b * LSEQ + row) * DH + 8 * half];
    bf16x8 qf[4], qn[4];
    #pragma unroll
    for (int kk = 0; kk < 4; ++kk)
        qf[kk] = *reinterpret_cast<const bf16x8*>(qb_all + (size_t)wid * 32 * DH + kk * 16);

    #pragma unroll
    for (int k = 0; k < 8; ++k) {
        const int lb = 8 * k + wid;
        if (k < 7) {
            const unsigned short* qnp = qb_all + (size_t)(lb + 8) * 32 * DH;
            #pragma unroll
            for (int kk = 0; kk < 4; ++kk)
                qn[kk] = *reinterpret_cast<const bf16x8*>(qnp + kk * 16);
        }
        const int nfull = (lb > c) ? ((lb - c + 7) >> 3) : 0;
        const bool has_diag = ((lb & 7) == c);
        f32x2 z2 = {0.f, 0.f}, o2 = {0.f, 0.f};
        if (nfull > 0 || has_diag) {
            int ti = 0;
            for (; ti + 1 < nfull; ti += 2) {   // ILP-2 over owned tiles
                bf16x8 ka[4], kc[4];
                lds_kfrag(Ks, ti, row, half, ka);
                lds_kfrag(Ks, ti + 1, row, half, kc);
                __builtin_amdgcn_s_setprio(1);
                f32x16 accA = mfma_tile(ka, qf);
                f32x16 accB = mfma_tile(kc, qf);
                __builtin_amdgcn_s_setprio(0);
                expacc(accA, &vt[ti][0], half, z2, o2);
                expacc(accB, &vt[ti + 1][0], half, z2, o2);
            }
            if (ti < nfull) {
                bf16x8 ka[4];
                lds_kfrag(Ks, ti, row, half, ka);
                f32x16 accA = mfma_tile(ka, qf);
                expacc(accA, &vt[ti][0], half, z2, o2);
            }
            if (has_diag) {
                const int td = nfull;
                bf16x8 ka[4];
                lds_kfrag(Ks, td, row, half, ka);
                f32x16 accA = mfma_tile(ka, qf);
                expacc_diag(accA, &vt[td][0], half, row, z2, o2);
            }
        }
        float z = z2[0] + z2[1];
        float o = o2[0] + o2[1];
        z += __shfl_xor(z, 32, 64);
        o += __shfl_xor(o, 32, 64);
        if (half == 0)
            zopart[((size_t)(b * 64 + lb) * CCH + c) * 32 + row] = float2{z, o};
        #pragma unroll
        for (int kk = 0; kk < 4; ++kk) qf[kk] = qn[kk];
    }
}

// ---- combine chunks: per (b,lb,col) -> o/z, block-reduce to 512 partials ----
__global__ __launch_bounds__(256) void attn_combine(const float2* __restrict__ zopart,
                                                    float* __restrict__ partials) {
    __shared__ float red[256];
    const int t = threadIdx.x;
    const int e = blockIdx.x * 256 + t;
    const int bl = e >> 5, col = e & 31;
    float z = 0.f, o = 0.f;
    #pragma unroll
    for (int c = 0; c < CCH; ++c) {
        float2 p = zopart[((size_t)bl * CCH + c) * 32 + col];
        z += p.x; o += p.y;
    }
    red[t] = o / z;
    __syncthreads();
    for (int sh = 128; sh > 0; sh >>= 1) {
        if (t < sh) red[t] += red[t + sh];
        __syncthreads();
    }
    if (t == 0) partials[blockIdx.x] = red[0];
}

// ---- final deterministic reduction of 512 partials ----
__global__ void reduce_kernel(const float* __restrict__ partials, float* __restrict__ out) {
    __shared__ float red[256];
    int t = threadIdx.x;
    red[t] = partials[t] + partials[t + 256];
    __syncthreads();
    for (int sh = 128; sh > 0; sh >>= 1) {
        if (t < sh) red[t] += red[t + sh];
        __syncthreads();
    }
    if (t == 0) out[0] = red[0];
}

extern "C" void kernel_launch(void* const* d_in, const int* in_sizes, int n_in,
                              void* d_out, int out_size, void* d_ws, size_t ws_size,
                              hipStream_t stream) {
    const float* x    = (const float*)d_in[0];
    const float* wqkv = (const float*)d_in[1];
    const float* wout = (const float*)d_in[2];
    float* out = (float*)d_out;

    unsigned short* qws = (unsigned short*)d_ws;
    unsigned short* kws = qws + (size_t)BH * LSEQ * DH;
    unsigned short* xb  = kws + (size_t)BH * LSEQ * DH;
    unsigned short* wb  = xb + (size_t)LSEQ * NB * EMB;
    float* vw       = (float*)(wb + (size_t)2 * EMB * EMB);
    float* wsum     = vw + (size_t)BH * LSEQ;
    float* wveff    = wsum + EMB;
    float* partials = wveff + NH * EMB;
    float* wpart    = partials + 1024;
    // zopart (8.4 MB) aliases xb (16 MB): proj_mfma (the only xb reader)
    // completes before attn_mfma writes; xb is rewritten every call (by vw).
    float2* zopart  = (float2*)xb;

    hipLaunchKernelGGL(prep_kernel,   dim3(1024 + 128), dim3(256), 0, stream,
                       wqkv, wout, wb, wpart);
    hipLaunchKernelGGL(wsum_final_kernel, dim3(EMB / 256), dim3(256), 0, stream, wpart, wsum);
    hipLaunchKernelGGL(wveff_kernel,  dim3(NH * EMB / 256), dim3(256), 0, stream, wqkv, wsum, wveff);
    hipLaunchKernelGGL(vw_kernel,     dim3(LSEQ * NB / 4), dim3(256), 0, stream, x, wveff, vw, xb);
    hipLaunchKernelGGL(proj_mfma,     dim3(1024), dim3(512), 0, stream,
                       xb, wb, qws, kws);
    hipLaunchKernelGGL(attn_mfma,     dim3(BH * CCH), dim3(512), 0, stream,
                       qws, kws, vw, zopart);
    hipLaunchKernelGGL(attn_combine,  dim3(512), dim3(256), 0, stream, zopart, partials);
    hipLaunchKernelGGL(reduce_kernel, dim3(1), dim3(256), 0, stream, partials, out);
}

// Round 23
// 111.944 us; speedup vs baseline: 1.3628x; 1.0467x over previous
//
#include <hip/hip_runtime.h>
#include <hip/hip_bf16.h>

#define LSEQ 2048
#define NB   4
#define EMB  1024
#define NH   16
#define DH   64
#define BH   (NB*NH)   // 64 head-batches
#define SCALE 0.125f   // d^-0.5
#define CCH  8         // K-tile chunks per b (block-level, stride-interleaved)
#define LOG2E 1.4426950408889634f
#define NEG16LOG2E (-23.083120654223414f)   // -16*log2e (acc C-init)

typedef unsigned short ushort8 __attribute__((ext_vector_type(8)));
typedef __attribute__((ext_vector_type(8))) short bf16x8;    // MFMA A/B frag (8 bf16)
typedef __attribute__((ext_vector_type(4))) float f32x4;     // 16x16 C/D frag
typedef __attribute__((ext_vector_type(16))) float f32x16;   // 32x32 C/D frag
typedef __attribute__((ext_vector_type(2))) float f32x2;     // packed z/o acc

#define EXP2F(x) __builtin_amdgcn_exp2f(x)   // v_exp_f32 (HW exp2)

// counted-vmcnt barrier primitives (raw s_barrier: no compiler vmcnt(0) drain)
#define WAITV4  asm volatile("s_waitcnt vmcnt(4)" ::: "memory")
#define WAITV0  asm volatile("s_waitcnt vmcnt(0)" ::: "memory")
#define RBAR    asm volatile("s_barrier" ::: "memory")

__device__ __forceinline__ unsigned short f_to_bf(float f) {
    unsigned int u = __float_as_uint(f);
    return (unsigned short)((u + 0x7fffu + ((u >> 16) & 1u)) >> 16);
}

__device__ __forceinline__ void gload_lds16(const void* g, void* l) {
    __builtin_amdgcn_global_load_lds(
        (const __attribute__((address_space(1))) unsigned int*)g,
        (__attribute__((address_space(3))) unsigned int*)l, 16, 0, 0);
}

// ---- prep: fused tobf16(wqkv) [blocks 0..1023] + wsum_part [1024..1151] ----
__global__ __launch_bounds__(256) void prep_kernel(const float* __restrict__ wqkv,
                                                   const float* __restrict__ wout,
                                                   unsigned short* __restrict__ wb,
                                                   float* __restrict__ wpart) {
    if (blockIdx.x < 1024) {
        int i = blockIdx.x * 256 + threadIdx.x;   // < 2*EMB*EMB/8
        const float4* p = reinterpret_cast<const float4*>(wqkv) + (size_t)i * 2;
        float4 a = p[0], b = p[1];
        ushort8 o;
        o[0] = f_to_bf(a.x); o[1] = f_to_bf(a.y); o[2] = f_to_bf(a.z); o[3] = f_to_bf(a.w);
        o[4] = f_to_bf(b.x); o[5] = f_to_bf(b.y); o[6] = f_to_bf(b.z); o[7] = f_to_bf(b.w);
        reinterpret_cast<ushort8*>(wb)[i] = o;
    } else {
        int bb = blockIdx.x - 1024;
        int fc = bb >> 2;
        int e  = (bb & 3) * 256 + threadIdx.x;
        float s = 0.f;
        #pragma unroll 8
        for (int f = fc * 32; f < fc * 32 + 32; ++f) s += wout[(size_t)f * EMB + e];
        wpart[(size_t)fc * EMB + e] = s;
    }
}

__global__ __launch_bounds__(256) void wsum_final_kernel(const float* __restrict__ wpart,
                                                         float* __restrict__ wsum) {
    int e = blockIdx.x * 256 + threadIdx.x;
    float s = 0.f;
    #pragma unroll
    for (int c = 0; c < 32; ++c) s += wpart[(size_t)c * EMB + e];
    wsum[e] = s;
}

// ---- wv_eff[h][e] = sum_j wqkv[2E + h*64 + j][e] * wsum[h*64+j] ----
__global__ void wveff_kernel(const float* __restrict__ wqkv, const float* __restrict__ wsum,
                             float* __restrict__ wveff) {
    int idx = blockIdx.x * 256 + threadIdx.x;   // h*EMB + e
    int h = idx >> 10, e = idx & 1023;
    float s = 0.f;
    #pragma unroll 8
    for (int j = 0; j < DH; ++j)
        s += wqkv[(size_t)(2 * EMB + h * DH + j) * EMB + e] * wsum[h * DH + j];
    wveff[idx] = s;
}

// ---- vw: 2 rows/thread share each wveff load (halves L2-bound wveff traffic
// 536->268 MB); stride-64 scalar keeps VGPR modest. Fused x->bf16. ----
__global__ __launch_bounds__(256) void vw_kernel(const float* __restrict__ x,
                                                 const float* __restrict__ wveff,
                                                 float* __restrict__ vw,
                                                 unsigned short* __restrict__ xb) {
    int wave = threadIdx.x >> 6;
    int lane = threadIdx.x & 63;
    int r0 = blockIdx.x * 8 + wave;       // rows r0 and r0+4
    int r1 = r0 + 4;
    float acc0[NH] = {}, acc1[NH] = {};
    for (int e = lane; e < EMB; e += 64) {
        float xe0 = x[(size_t)r0 * EMB + e];
        float xe1 = x[(size_t)r1 * EMB + e];
        xb[(size_t)r0 * EMB + e] = f_to_bf(xe0);
        xb[(size_t)r1 * EMB + e] = f_to_bf(xe1);
        #pragma unroll
        for (int h = 0; h < NH; ++h) {
            float wv = wveff[h * EMB + e];
            acc0[h] += xe0 * wv;
            acc1[h] += xe1 * wv;
        }
    }
    int n0 = r0 & 3, l0 = r0 >> 2;
    int n1 = r1 & 3, l1 = r1 >> 2;
    #pragma unroll
    for (int h = 0; h < NH; ++h) {
        float v0 = acc0[h], v1 = acc1[h];
        #pragma unroll
        for (int off = 32; off > 0; off >>= 1) {
            v0 += __shfl_down(v0, off, 64);
            v1 += __shfl_down(v1, off, 64);
        }
        if (lane == 0) {
            vw[(size_t)(n0 * NH + h) * LSEQ + l0] = v0;
            vw[(size_t)(n1 * NH + h) * LSEQ + l1] = v1;
        }
    }
}

// ---- bf16 MFMA Q/K projection: PBK=64 dbuf, 8 waves, counted-vmcnt (R22) ----
#define PBM 128
#define PBN 128
#define PBK 64
#define BUFS ((PBM + PBN) * PBK)   // shorts per buffer (32 KB)

__device__ __forceinline__ void proj_stage(const unsigned short* __restrict__ xb,
                                           const unsigned short* __restrict__ wb,
                                           unsigned short* As, unsigned short* Bs,
                                           int r0, int c0, int k0, int wid, int srow, int sj) {
    #pragma unroll
    for (int i = 0; i < 2; ++i) {
        int seg = wid * 2 + i;                    // 16 segments of 8 rows
        gload_lds16(&xb[(size_t)(r0 + seg * 8 + srow) * EMB + k0 + sj], &As[seg * 8 * PBK]);
        gload_lds16(&wb[(size_t)(c0 + seg * 8 + srow) * EMB + k0 + sj], &Bs[seg * 8 * PBK]);
    }
}

__device__ __forceinline__ void proj_compute(const unsigned short* As, const unsigned short* Bs,
                                             int wr, int wc, int col, int g, f32x4 (&acc)[4][2]) {
    #pragma unroll
    for (int kk = 0; kk < 2; ++kk) {
        bf16x8 af[4], bff[2];
        #pragma unroll
        for (int m = 0; m < 4; ++m) {
            int row = wr * 64 + m * 16 + col;
            af[m] = *reinterpret_cast<const bf16x8*>(
                &As[row * PBK + (((kk * 4 + g) ^ (row & 7)) * 8)]);
        }
        #pragma unroll
        for (int n = 0; n < 2; ++n) {
            int row = wc * 32 + n * 16 + col;
            bff[n] = *reinterpret_cast<const bf16x8*>(
                &Bs[row * PBK + (((kk * 4 + g) ^ (row & 7)) * 8)]);
        }
        #pragma unroll
        for (int m = 0; m < 4; ++m)
            #pragma unroll
            for (int n = 0; n < 2; ++n)
                acc[m][n] = __builtin_amdgcn_mfma_f32_16x16x32_bf16(af[m], bff[n], acc[m][n], 0, 0, 0);
    }
}

__global__ __launch_bounds__(512) void proj_mfma(const unsigned short* __restrict__ xb,
                                                 const unsigned short* __restrict__ wb,
                                                 unsigned short* __restrict__ qws,
                                                 unsigned short* __restrict__ kws) {
    __shared__ unsigned short SMEM[2 * BUFS];   // 64 KB (dbuf)
    unsigned short* As0 = SMEM;
    unsigned short* Bs0 = SMEM + PBM * PBK;
    unsigned short* As1 = SMEM + BUFS;
    unsigned short* Bs1 = As1 + PBM * PBK;
    const int tid  = threadIdx.x;
    const int lane = tid & 63;
    const int wid  = tid >> 6;                 // 0..7
    const int wr   = wid >> 2, wc = wid & 3;   // 2x4 wave grid, wave tile 64x32
    const int d  = blockIdx.x;
    const int w  = (d & 7) * 128 + (d >> 3);
    const int r0 = (w >> 4) * PBM;
    const int c0 = (w & 15) * PBN;
    const int col  = lane & 15, g = lane >> 4;

    f32x4 acc[4][2];
    #pragma unroll
    for (int m = 0; m < 4; ++m)
        #pragma unroll
        for (int n = 0; n < 2; ++n) acc[m][n] = f32x4{0.f, 0.f, 0.f, 0.f};

    const int srow = lane >> 3;
    const int sj   = ((lane & 7) ^ (lane >> 3)) * 8;

    proj_stage(xb, wb, As0, Bs0, r0, c0, 0, wid, srow, sj);
    WAITV0; RBAR;
    #pragma unroll 1
    for (int t = 0; t < 16; t += 2) {
        proj_stage(xb, wb, As1, Bs1, r0, c0, (t + 1) * PBK, wid, srow, sj);
        WAITV4; RBAR;                 // buf0 ready; buf1's 4 loads stay in flight
        proj_compute(As0, Bs0, wr, wc, col, g, acc);
        RBAR;                         // WAR: all buf0 reads done before re-stage
        if (t + 2 < 16) {
            proj_stage(xb, wb, As0, Bs0, r0, c0, (t + 2) * PBK, wid, srow, sj);
            WAITV4;
        } else {
            WAITV0;                   // tail: nothing in flight behind buf1
        }
        RBAR;
        proj_compute(As1, Bs1, wr, wc, col, g, acc);
        RBAR;
    }

    const float scl = (c0 < EMB) ? SCALE * LOG2E : 1.0f;   // block is purely Q or K
    #pragma unroll
    for (int m = 0; m < 4; ++m) {
        #pragma unroll
        for (int n = 0; n < 2; ++n) {
            #pragma unroll
            for (int j = 0; j < 4; ++j) {
                int row = wr * 64 + m * 16 + g * 4 + j;
                int cc  = wc * 32 + n * 16 + col;
                SMEM[row * 128 + (((cc >> 3) ^ (row & 7)) * 8) + (cc & 7)] =
                    f_to_bf(acc[m][n][j] * scl);
            }
        }
    }
    __syncthreads();
    #pragma unroll
    for (int pass = 0; pass < 4; ++pass) {
        int unit = pass * 64 + (tid >> 3);   // 0..255 = (row, half)
        int r    = unit >> 1;
        int hsel = unit & 1;
        int pg   = (tid & 7) ^ (r & 7);
        ushort8 u = *reinterpret_cast<const ushort8*>(
            &SMEM[r * 128 + (hsel * 8 + (tid & 7)) * 8]);
        int rg = r0 + r;
        int nb = rg & 3, l = rg >> 2;
        int cbase = c0 + hsel * 64;
        unsigned short* dstp;
        if (c0 < EMB) {
            dstp = &qws[((size_t)(nb * NH + (cbase >> 6)) * LSEQ + l) * DH];
        } else {
            int c2 = cbase - EMB;
            dstp = &kws[((size_t)(nb * NH + (c2 >> 6)) * LSEQ + l) * DH];
        }
        *reinterpret_cast<ushort8*>(dstp + pg * 8) = u;
    }
}

// ---- attn helpers ----
__device__ __forceinline__ void lds_kfrag(const unsigned short* Ks, int ti, int m, int half,
                                          bf16x8* kf) {
    const char* base = reinterpret_cast<const char*>(Ks);
    #pragma unroll
    for (int kk = 0; kk < 4; ++kk) {
        int byte = ti * 4096 + m * 128 + ((half * 16 + kk * 32) ^ ((m & 7) << 4));
        kf[kk] = *reinterpret_cast<const bf16x8*>(base + byte);
    }
}
__device__ __forceinline__ f32x16 mfma_tile(const bf16x8* kf, const bf16x8* qf) {
    f32x16 acc;
    #pragma unroll
    for (int j = 0; j < 16; ++j) acc[j] = NEG16LOG2E;
    #pragma unroll
    for (int kk = 0; kk < 4; ++kk)
        acc = __builtin_amdgcn_mfma_f32_32x32x16_bf16(kf[kk], qf[kk], acc, 0, 0, 0);
    return acc;
}
__device__ __forceinline__ void expacc(const f32x16& acc, const float* vt, int half,
                                       f32x2& z2, f32x2& o2) {
    #pragma unroll
    for (int q = 0; q < 4; ++q) {
        float4 v4 = *reinterpret_cast<const float4*>(&vt[8 * q + 4 * half]);
        f32x2 p01 = {EXP2F(acc[4 * q + 0]), EXP2F(acc[4 * q + 1])};
        f32x2 p23 = {EXP2F(acc[4 * q + 2]), EXP2F(acc[4 * q + 3])};
        f32x2 v01 = {v4.x, v4.y};
        f32x2 v23 = {v4.z, v4.w};
        z2 += p01;
        o2 += p01 * v01;
        z2 += p23;
        o2 += p23 * v23;
    }
}
__device__ __forceinline__ void expacc_diag(const f32x16& acc, const float* vt, int half,
                                            int row, f32x2& z2, f32x2& o2) {
    #pragma unroll
    for (int q = 0; q < 4; ++q) {
        float4 v4 = *reinterpret_cast<const float4*>(&vt[8 * q + 4 * half]);
        float vvq[4] = {v4.x, v4.y, v4.z, v4.w};
        #pragma unroll
        for (int j = 0; j < 4; ++j) {
            int mrow = j + 8 * q + 4 * half;
            float p = EXP2F(acc[4 * q + j]);
            p = (mrow <= row) ? p : 0.f;   // causal on diagonal tile
            z2[0] += p;
            o2[0] += p * vvq[j];
        }
    }
}

// ---- K-stationary MFMA causal attention (Q prefetched across l-blocks) ----
__global__ __launch_bounds__(512) void attn_mfma(const unsigned short* __restrict__ qws,
                                                 const unsigned short* __restrict__ kws,
                                                 const float* __restrict__ vw,
                                                 float2* __restrict__ zopart) {
    __shared__ unsigned short Ks[CCH * 2048];   // 8 tiles x 4KB = 32KB
    __shared__ float vt[CCH][32];               // vw values for owned tiles
    const int tid = threadIdx.x;
    const int b   = blockIdx.x & 63;            // low bits: all chunks of b on one XCD
    const int c   = blockIdx.x >> 6;

    {
        int ti = tid >> 6, lane = tid & 63;
        int row = lane >> 1, hb = lane & 1;
        const unsigned short* src = &kws[((size_t)b * LSEQ + (c + CCH * ti) * 32 + row) * DH + hb * 32];
        char* dst = reinterpret_cast<char*>(Ks) + ti * 4096 + row * 128;
        #pragma unroll
        for (int s = 0; s < 4; ++s) {
            ushort8 u = *reinterpret_cast<const ushort8*>(src + s * 8);
            *reinterpret_cast<ushort8*>(dst + ((hb * 64 + s * 16) ^ ((row & 7) << 4))) = u;
        }
        if (tid < 256) vt[tid >> 5][tid & 31] =
            vw[(size_t)b * LSEQ + (c + CCH * (tid >> 5)) * 32 + (tid & 31)];
    }
    __syncthreads();

    const int wid  = tid >> 6;
    const int lane = tid & 63;
    const int row  = lane & 31;
    const int half = lane >> 5;

    const unsigned short* qb_all = &qws[((size_t)b * LSEQ + row) * DH + 8 * half];
    bf16x8 qf[4], qn[4];
    #pragma unroll
    for (int kk = 0; kk < 4; ++kk)
        qf[kk] = *reinterpret_cast<const bf16x8*>(qb_all + (size_t)wid * 32 * DH + kk * 16);

    #pragma unroll
    for (int k = 0; k < 8; ++k) {
        const int lb = 8 * k + wid;
        if (k < 7) {
            const unsigned short* qnp = qb_all + (size_t)(lb + 8) * 32 * DH;
            #pragma unroll
            for (int kk = 0; kk < 4; ++kk)
                qn[kk] = *reinterpret_cast<const bf16x8*>(qnp + kk * 16);
        }
        const int nfull = (lb > c) ? ((lb - c + 7) >> 3) : 0;
        const bool has_diag = ((lb & 7) == c);
        f32x2 z2 = {0.f, 0.f}, o2 = {0.f, 0.f};
        if (nfull > 0 || has_diag) {
            int ti = 0;
            for (; ti + 1 < nfull; ti += 2) {   // ILP-2 over owned tiles
                bf16x8 ka[4], kc[4];
                lds_kfrag(Ks, ti, row, half, ka);
                lds_kfrag(Ks, ti + 1, row, half, kc);
                __builtin_amdgcn_s_setprio(1);
                f32x16 accA = mfma_tile(ka, qf);
                f32x16 accB = mfma_tile(kc, qf);
                __builtin_amdgcn_s_setprio(0);
                expacc(accA, &vt[ti][0], half, z2, o2);
                expacc(accB, &vt[ti + 1][0], half, z2, o2);
            }
            if (ti < nfull) {
                bf16x8 ka[4];
                lds_kfrag(Ks, ti, row, half, ka);
                f32x16 accA = mfma_tile(ka, qf);
                expacc(accA, &vt[ti][0], half, z2, o2);
            }
            if (has_diag) {
                const int td = nfull;
                bf16x8 ka[4];
                lds_kfrag(Ks, td, row, half, ka);
                f32x16 accA = mfma_tile(ka, qf);
                expacc_diag(accA, &vt[td][0], half, row, z2, o2);
            }
        }
        float z = z2[0] + z2[1];
        float o = o2[0] + o2[1];
        z += __shfl_xor(z, 32, 64);
        o += __shfl_xor(o, 32, 64);
        if (half == 0)
            zopart[((size_t)(b * 64 + lb) * CCH + c) * 32 + row] = float2{z, o};
        #pragma unroll
        for (int kk = 0; kk < 4; ++kk) qf[kk] = qn[kk];
    }
}

// ---- combine chunks: per (b,lb,col) -> o/z, block-reduce to 512 partials ----
__global__ __launch_bounds__(256) void attn_combine(const float2* __restrict__ zopart,
                                                    float* __restrict__ partials) {
    __shared__ float red[256];
    const int t = threadIdx.x;
    const int e = blockIdx.x * 256 + t;
    const int bl = e >> 5, col = e & 31;
    float z = 0.f, o = 0.f;
    #pragma unroll
    for (int c = 0; c < CCH; ++c) {
        float2 p = zopart[((size_t)bl * CCH + c) * 32 + col];
        z += p.x; o += p.y;
    }
    red[t] = o / z;
    __syncthreads();
    for (int sh = 128; sh > 0; sh >>= 1) {
        if (t < sh) red[t] += red[t + sh];
        __syncthreads();
    }
    if (t == 0) partials[blockIdx.x] = red[0];
}

// ---- final deterministic reduction of 512 partials ----
__global__ void reduce_kernel(const float* __restrict__ partials, float* __restrict__ out) {
    __shared__ float red[256];
    int t = threadIdx.x;
    red[t] = partials[t] + partials[t + 256];
    __syncthreads();
    for (int sh = 128; sh > 0; sh >>= 1) {
        if (t < sh) red[t] += red[t + sh];
        __syncthreads();
    }
    if (t == 0) out[0] = red[0];
}

extern "C" void kernel_launch(void* const* d_in, const int* in_sizes, int n_in,
                              void* d_out, int out_size, void* d_ws, size_t ws_size,
                              hipStream_t stream) {
    const float* x    = (const float*)d_in[0];
    const float* wqkv = (const float*)d_in[1];
    const float* wout = (const float*)d_in[2];
    float* out = (float*)d_out;

    unsigned short* qws = (unsigned short*)d_ws;
    unsigned short* kws = qws + (size_t)BH * LSEQ * DH;
    unsigned short* xb  = kws + (size_t)BH * LSEQ * DH;
    unsigned short* wb  = xb + (size_t)LSEQ * NB * EMB;
    float* vw       = (float*)(wb + (size_t)2 * EMB * EMB);
    float* wsum     = vw + (size_t)BH * LSEQ;
    float* wveff    = wsum + EMB;
    float* partials = wveff + NH * EMB;
    float* wpart    = partials + 1024;
    // zopart (8.4 MB) aliases xb (16 MB): proj_mfma (the only xb reader)
    // completes before attn_mfma writes; xb is rewritten every call (by vw).
    float2* zopart  = (float2*)xb;

    hipLaunchKernelGGL(prep_kernel,   dim3(1024 + 128), dim3(256), 0, stream,
                       wqkv, wout, wb, wpart);
    hipLaunchKernelGGL(wsum_final_kernel, dim3(EMB / 256), dim3(256), 0, stream, wpart, wsum);
    hipLaunchKernelGGL(wveff_kernel,  dim3(NH * EMB / 256), dim3(256), 0, stream, wqkv, wsum, wveff);
    hipLaunchKernelGGL(vw_kernel,     dim3(LSEQ * NB / 8), dim3(256), 0, stream, x, wveff, vw, xb);
    hipLaunchKernelGGL(proj_mfma,     dim3(1024), dim3(512), 0, stream,
                       xb, wb, qws, kws);
    hipLaunchKernelGGL(attn_mfma,     dim3(BH * CCH), dim3(512), 0, stream,
                       qws, kws, vw, zopart);
    hipLaunchKernelGGL(attn_combine,  dim3(512), dim3(256), 0, stream, zopart, partials);
    hipLaunchKernelGGL(reduce_kernel, dim3(1), dim3(256), 0, stream, partials, out);
}

// Round 24
// 111.029 us; speedup vs baseline: 1.3741x; 1.0082x over previous
//
#include <hip/hip_runtime.h>
#include <hip/hip_bf16.h>

#define LSEQ 2048
#define NB   4
#define EMB  1024
#define NH   16
#define DH   64
#define BH   (NB*NH)   // 64 head-batches
#define SCALE 0.125f   // d^-0.5
#define CCH  8         // K-tile chunks per b (block-level, stride-interleaved)
#define LOG2E 1.4426950408889634f
#define NEG16LOG2E (-23.083120654223414f)   // -16*log2e (acc C-init)

typedef unsigned short ushort8 __attribute__((ext_vector_type(8)));
typedef __attribute__((ext_vector_type(8))) short bf16x8;    // MFMA A/B frag (8 bf16)
typedef __attribute__((ext_vector_type(4))) float f32x4;     // 16x16 C/D frag
typedef __attribute__((ext_vector_type(16))) float f32x16;   // 32x32 C/D frag
typedef __attribute__((ext_vector_type(2))) float f32x2;     // packed z/o acc

#define EXP2F(x) __builtin_amdgcn_exp2f(x)   // v_exp_f32 (HW exp2)

// counted-vmcnt barrier primitives (raw s_barrier: no compiler vmcnt(0) drain)
#define WAITV4  asm volatile("s_waitcnt vmcnt(4)" ::: "memory")
#define WAITV0  asm volatile("s_waitcnt vmcnt(0)" ::: "memory")
#define RBAR    asm volatile("s_barrier" ::: "memory")

__device__ __forceinline__ unsigned short f_to_bf(float f) {
    unsigned int u = __float_as_uint(f);
    return (unsigned short)((u + 0x7fffu + ((u >> 16) & 1u)) >> 16);
}

__device__ __forceinline__ void gload_lds16(const void* g, void* l) {
    __builtin_amdgcn_global_load_lds(
        (const __attribute__((address_space(1))) unsigned int*)g,
        (__attribute__((address_space(3))) unsigned int*)l, 16, 0, 0);
}

// ---- prep: fused tobf16(wqkv) [blocks 0..1023] + wsum_part [1024..1151] ----
__global__ __launch_bounds__(256) void prep_kernel(const float* __restrict__ wqkv,
                                                   const float* __restrict__ wout,
                                                   unsigned short* __restrict__ wb,
                                                   float* __restrict__ wpart) {
    if (blockIdx.x < 1024) {
        int i = blockIdx.x * 256 + threadIdx.x;   // < 2*EMB*EMB/8
        const float4* p = reinterpret_cast<const float4*>(wqkv) + (size_t)i * 2;
        float4 a = p[0], b = p[1];
        ushort8 o;
        o[0] = f_to_bf(a.x); o[1] = f_to_bf(a.y); o[2] = f_to_bf(a.z); o[3] = f_to_bf(a.w);
        o[4] = f_to_bf(b.x); o[5] = f_to_bf(b.y); o[6] = f_to_bf(b.z); o[7] = f_to_bf(b.w);
        reinterpret_cast<ushort8*>(wb)[i] = o;
    } else {
        int bb = blockIdx.x - 1024;
        int fc = bb >> 2;
        int e  = (bb & 3) * 256 + threadIdx.x;
        float s = 0.f;
        #pragma unroll 8
        for (int f = fc * 32; f < fc * 32 + 32; ++f) s += wout[(size_t)f * EMB + e];
        wpart[(size_t)fc * EMB + e] = s;
    }
}

// ---- wveff with in-block wsum recompute (fuses old wsum_final kernel) ----
// block handles (h = blk>>2, e-range (blk&3)*256): first rebuild ws[64] =
// wsum[h*64 .. h*64+64) from wpart (8 loads/thread + LDS reduce), then
// wveff[h][e] = sum_j wqkv[2E + h*64 + j][e] * ws[j].
__global__ __launch_bounds__(256) void wveff_kernel(const float* __restrict__ wqkv,
                                                    const float* __restrict__ wpart,
                                                    float* __restrict__ wveff) {
    __shared__ float psum[4][64];
    __shared__ float ws[64];
    const int tid = threadIdx.x;
    const int h   = blockIdx.x >> 2;
    {
        int v = tid & 63, q = tid >> 6;
        float s = 0.f;
        #pragma unroll
        for (int cc = q * 8; cc < q * 8 + 8; ++cc)
            s += wpart[(size_t)cc * EMB + h * 64 + v];
        psum[q][v] = s;
    }
    __syncthreads();
    if (tid < 64) ws[tid] = psum[0][tid] + psum[1][tid] + psum[2][tid] + psum[3][tid];
    __syncthreads();
    int e = (blockIdx.x & 3) * 256 + tid;
    float s = 0.f;
    #pragma unroll 8
    for (int j = 0; j < 64; ++j)
        s += wqkv[(size_t)(2 * EMB + h * 64 + j) * EMB + e] * ws[j];
    wveff[h * EMB + e] = s;
}

// ---- vw: 4 rows/thread share each wveff load (wveff L2 traffic 268->134 MB);
// scalar stride-64 loads keep VGPR bounded (R20 float4 variant blew up). ----
__global__ __launch_bounds__(256) void vw_kernel(const float* __restrict__ x,
                                                 const float* __restrict__ wveff,
                                                 float* __restrict__ vw,
                                                 unsigned short* __restrict__ xb) {
    int wave = threadIdx.x >> 6;
    int lane = threadIdx.x & 63;
    int r0 = blockIdx.x * 16 + wave;       // rows r0, r0+4, r0+8, r0+12
    float acc0[NH] = {}, acc1[NH] = {}, acc2[NH] = {}, acc3[NH] = {};
    for (int e = lane; e < EMB; e += 64) {
        float xe0 = x[(size_t)r0 * EMB + e];
        float xe1 = x[(size_t)(r0 + 4) * EMB + e];
        float xe2 = x[(size_t)(r0 + 8) * EMB + e];
        float xe3 = x[(size_t)(r0 + 12) * EMB + e];
        xb[(size_t)r0 * EMB + e]        = f_to_bf(xe0);
        xb[(size_t)(r0 + 4) * EMB + e]  = f_to_bf(xe1);
        xb[(size_t)(r0 + 8) * EMB + e]  = f_to_bf(xe2);
        xb[(size_t)(r0 + 12) * EMB + e] = f_to_bf(xe3);
        #pragma unroll
        for (int h = 0; h < NH; ++h) {
            float wv = wveff[h * EMB + e];
            acc0[h] += xe0 * wv;
            acc1[h] += xe1 * wv;
            acc2[h] += xe2 * wv;
            acc3[h] += xe3 * wv;
        }
    }
    #pragma unroll
    for (int h = 0; h < NH; ++h) {
        float v0 = acc0[h], v1 = acc1[h], v2 = acc2[h], v3 = acc3[h];
        #pragma unroll
        for (int off = 32; off > 0; off >>= 1) {
            v0 += __shfl_down(v0, off, 64);
            v1 += __shfl_down(v1, off, 64);
            v2 += __shfl_down(v2, off, 64);
            v3 += __shfl_down(v3, off, 64);
        }
        if (lane == 0) {
            #pragma unroll
            for (int rr = 0; rr < 4; ++rr) {
                int r = r0 + rr * 4;
                float v = (rr == 0) ? v0 : (rr == 1) ? v1 : (rr == 2) ? v2 : v3;
                vw[(size_t)((r & 3) * NH + h) * LSEQ + (r >> 2)] = v;
            }
        }
    }
}

// ---- bf16 MFMA Q/K projection: PBK=64 dbuf, 8 waves, counted-vmcnt (R22) ----
#define PBM 128
#define PBN 128
#define PBK 64
#define BUFS ((PBM + PBN) * PBK)   // shorts per buffer (32 KB)

__device__ __forceinline__ void proj_stage(const unsigned short* __restrict__ xb,
                                           const unsigned short* __restrict__ wb,
                                           unsigned short* As, unsigned short* Bs,
                                           int r0, int c0, int k0, int wid, int srow, int sj) {
    #pragma unroll
    for (int i = 0; i < 2; ++i) {
        int seg = wid * 2 + i;                    // 16 segments of 8 rows
        gload_lds16(&xb[(size_t)(r0 + seg * 8 + srow) * EMB + k0 + sj], &As[seg * 8 * PBK]);
        gload_lds16(&wb[(size_t)(c0 + seg * 8 + srow) * EMB + k0 + sj], &Bs[seg * 8 * PBK]);
    }
}

__device__ __forceinline__ void proj_compute(const unsigned short* As, const unsigned short* Bs,
                                             int wr, int wc, int col, int g, f32x4 (&acc)[4][2]) {
    #pragma unroll
    for (int kk = 0; kk < 2; ++kk) {
        bf16x8 af[4], bff[2];
        #pragma unroll
        for (int m = 0; m < 4; ++m) {
            int row = wr * 64 + m * 16 + col;
            af[m] = *reinterpret_cast<const bf16x8*>(
                &As[row * PBK + (((kk * 4 + g) ^ (row & 7)) * 8)]);
        }
        #pragma unroll
        for (int n = 0; n < 2; ++n) {
            int row = wc * 32 + n * 16 + col;
            bff[n] = *reinterpret_cast<const bf16x8*>(
                &Bs[row * PBK + (((kk * 4 + g) ^ (row & 7)) * 8)]);
        }
        #pragma unroll
        for (int m = 0; m < 4; ++m)
            #pragma unroll
            for (int n = 0; n < 2; ++n)
                acc[m][n] = __builtin_amdgcn_mfma_f32_16x16x32_bf16(af[m], bff[n], acc[m][n], 0, 0, 0);
    }
}

__global__ __launch_bounds__(512) void proj_mfma(const unsigned short* __restrict__ xb,
                                                 const unsigned short* __restrict__ wb,
                                                 unsigned short* __restrict__ qws,
                                                 unsigned short* __restrict__ kws) {
    __shared__ unsigned short SMEM[2 * BUFS];   // 64 KB (dbuf)
    unsigned short* As0 = SMEM;
    unsigned short* Bs0 = SMEM + PBM * PBK;
    unsigned short* As1 = SMEM + BUFS;
    unsigned short* Bs1 = As1 + PBM * PBK;
    const int tid  = threadIdx.x;
    const int lane = tid & 63;
    const int wid  = tid >> 6;                 // 0..7
    const int wr   = wid >> 2, wc = wid & 3;   // 2x4 wave grid, wave tile 64x32
    const int d  = blockIdx.x;
    const int w  = (d & 7) * 128 + (d >> 3);
    const int r0 = (w >> 4) * PBM;
    const int c0 = (w & 15) * PBN;
    const int col  = lane & 15, g = lane >> 4;

    f32x4 acc[4][2];
    #pragma unroll
    for (int m = 0; m < 4; ++m)
        #pragma unroll
        for (int n = 0; n < 2; ++n) acc[m][n] = f32x4{0.f, 0.f, 0.f, 0.f};

    const int srow = lane >> 3;
    const int sj   = ((lane & 7) ^ (lane >> 3)) * 8;

    proj_stage(xb, wb, As0, Bs0, r0, c0, 0, wid, srow, sj);
    WAITV0; RBAR;
    #pragma unroll 1
    for (int t = 0; t < 16; t += 2) {
        proj_stage(xb, wb, As1, Bs1, r0, c0, (t + 1) * PBK, wid, srow, sj);
        WAITV4; RBAR;                 // buf0 ready; buf1's 4 loads stay in flight
        proj_compute(As0, Bs0, wr, wc, col, g, acc);
        RBAR;                         // WAR: all buf0 reads done before re-stage
        if (t + 2 < 16) {
            proj_stage(xb, wb, As0, Bs0, r0, c0, (t + 2) * PBK, wid, srow, sj);
            WAITV4;
        } else {
            WAITV0;                   // tail: nothing in flight behind buf1
        }
        RBAR;
        proj_compute(As1, Bs1, wr, wc, col, g, acc);
        RBAR;
    }

    const float scl = (c0 < EMB) ? SCALE * LOG2E : 1.0f;   // block is purely Q or K
    #pragma unroll
    for (int m = 0; m < 4; ++m) {
        #pragma unroll
        for (int n = 0; n < 2; ++n) {
            #pragma unroll
            for (int j = 0; j < 4; ++j) {
                int row = wr * 64 + m * 16 + g * 4 + j;
                int cc  = wc * 32 + n * 16 + col;
                SMEM[row * 128 + (((cc >> 3) ^ (row & 7)) * 8) + (cc & 7)] =
                    f_to_bf(acc[m][n][j] * scl);
            }
        }
    }
    __syncthreads();
    #pragma unroll
    for (int pass = 0; pass < 4; ++pass) {
        int unit = pass * 64 + (tid >> 3);   // 0..255 = (row, half)
        int r    = unit >> 1;
        int hsel = unit & 1;
        int pg   = (tid & 7) ^ (r & 7);
        ushort8 u = *reinterpret_cast<const ushort8*>(
            &SMEM[r * 128 + (hsel * 8 + (tid & 7)) * 8]);
        int rg = r0 + r;
        int nb = rg & 3, l = rg >> 2;
        int cbase = c0 + hsel * 64;
        unsigned short* dstp;
        if (c0 < EMB) {
            dstp = &qws[((size_t)(nb * NH + (cbase >> 6)) * LSEQ + l) * DH];
        } else {
            int c2 = cbase - EMB;
            dstp = &kws[((size_t)(nb * NH + (c2 >> 6)) * LSEQ + l) * DH];
        }
        *reinterpret_cast<ushort8*>(dstp + pg * 8) = u;
    }
}

// ---- attn helpers ----
__device__ __forceinline__ void lds_kfrag(const unsigned short* Ks, int ti, int m, int half,
                                          bf16x8* kf) {
    const char* base = reinterpret_cast<const char*>(Ks);
    #pragma unroll
    for (int kk = 0; kk < 4; ++kk) {
        int byte = ti * 4096 + m * 128 + ((half * 16 + kk * 32) ^ ((m & 7) << 4));
        kf[kk] = *reinterpret_cast<const bf16x8*>(base + byte);
    }
}
__device__ __forceinline__ f32x16 mfma_tile(const bf16x8* kf, const bf16x8* qf) {
    f32x16 acc;
    #pragma unroll
    for (int j = 0; j < 16; ++j) acc[j] = NEG16LOG2E;
    #pragma unroll
    for (int kk = 0; kk < 4; ++kk)
        acc = __builtin_amdgcn_mfma_f32_32x32x16_bf16(kf[kk], qf[kk], acc, 0, 0, 0);
    return acc;
}
__device__ __forceinline__ void expacc(const f32x16& acc, const float* vt, int half,
                                       f32x2& z2, f32x2& o2) {
    #pragma unroll
    for (int q = 0; q < 4; ++q) {
        float4 v4 = *reinterpret_cast<const float4*>(&vt[8 * q + 4 * half]);
        f32x2 p01 = {EXP2F(acc[4 * q + 0]), EXP2F(acc[4 * q + 1])};
        f32x2 p23 = {EXP2F(acc[4 * q + 2]), EXP2F(acc[4 * q + 3])};
        f32x2 v01 = {v4.x, v4.y};
        f32x2 v23 = {v4.z, v4.w};
        z2 += p01;
        o2 += p01 * v01;
        z2 += p23;
        o2 += p23 * v23;
    }
}
__device__ __forceinline__ void expacc_diag(const f32x16& acc, const float* vt, int half,
                                            int row, f32x2& z2, f32x2& o2) {
    #pragma unroll
    for (int q = 0; q < 4; ++q) {
        float4 v4 = *reinterpret_cast<const float4*>(&vt[8 * q + 4 * half]);
        float vvq[4] = {v4.x, v4.y, v4.z, v4.w};
        #pragma unroll
        for (int j = 0; j < 4; ++j) {
            int mrow = j + 8 * q + 4 * half;
            float p = EXP2F(acc[4 * q + j]);
            p = (mrow <= row) ? p : 0.f;   // causal on diagonal tile
            z2[0] += p;
            o2[0] += p * vvq[j];
        }
    }
}

// ---- K-stationary MFMA causal attention (Q prefetched across l-blocks) ----
__global__ __launch_bounds__(512) void attn_mfma(const unsigned short* __restrict__ qws,
                                                 const unsigned short* __restrict__ kws,
                                                 const float* __restrict__ vw,
                                                 float2* __restrict__ zopart) {
    __shared__ unsigned short Ks[CCH * 2048];   // 8 tiles x 4KB = 32KB
    __shared__ float vt[CCH][32];               // vw values for owned tiles
    const int tid = threadIdx.x;
    const int b   = blockIdx.x & 63;            // low bits: all chunks of b on one XCD
    const int c   = blockIdx.x >> 6;

    {
        int ti = tid >> 6, lane = tid & 63;
        int row = lane >> 1, hb = lane & 1;
        const unsigned short* src = &kws[((size_t)b * LSEQ + (c + CCH * ti) * 32 + row) * DH + hb * 32];
        char* dst = reinterpret_cast<char*>(Ks) + ti * 4096 + row * 128;
        #pragma unroll
        for (int s = 0; s < 4; ++s) {
            ushort8 u = *reinterpret_cast<const ushort8*>(src + s * 8);
            *reinterpret_cast<ushort8*>(dst + ((hb * 64 + s * 16) ^ ((row & 7) << 4))) = u;
        }
        if (tid < 256) vt[tid >> 5][tid & 31] =
            vw[(size_t)b * LSEQ + (c + CCH * (tid >> 5)) * 32 + (tid & 31)];
    }
    __syncthreads();

    const int wid  = tid >> 6;
    const int lane = tid & 63;
    const int row  = lane & 31;
    const int half = lane >> 5;

    const unsigned short* qb_all = &qws[((size_t)b * LSEQ + row) * DH + 8 * half];
    bf16x8 qf[4], qn[4];
    #pragma unroll
    for (int kk = 0; kk < 4; ++kk)
        qf[kk] = *reinterpret_cast<const bf16x8*>(qb_all + (size_t)wid * 32 * DH + kk * 16);

    #pragma unroll
    for (int k = 0; k < 8; ++k) {
        const int lb = 8 * k + wid;
        if (k < 7) {
            const unsigned short* qnp = qb_all + (size_t)(lb + 8) * 32 * DH;
            #pragma unroll
            for (int kk = 0; kk < 4; ++kk)
                qn[kk] = *reinterpret_cast<const bf16x8*>(qnp + kk * 16);
        }
        const int nfull = (lb > c) ? ((lb - c + 7) >> 3) : 0;
        const bool has_diag = ((lb & 7) == c);
        f32x2 z2 = {0.f, 0.f}, o2 = {0.f, 0.f};
        if (nfull > 0 || has_diag) {
            int ti = 0;
            for (; ti + 1 < nfull; ti += 2) {   // ILP-2 over owned tiles
                bf16x8 ka[4], kc[4];
                lds_kfrag(Ks, ti, row, half, ka);
                lds_kfrag(Ks, ti + 1, row, half, kc);
                __builtin_amdgcn_s_setprio(1);
                f32x16 accA = mfma_tile(ka, qf);
                f32x16 accB = mfma_tile(kc, qf);
                __builtin_amdgcn_s_setprio(0);
                expacc(accA, &vt[ti][0], half, z2, o2);
                expacc(accB, &vt[ti + 1][0], half, z2, o2);
            }
            if (ti < nfull) {
                bf16x8 ka[4];
                lds_kfrag(Ks, ti, row, half, ka);
                f32x16 accA = mfma_tile(ka, qf);
                expacc(accA, &vt[ti][0], half, z2, o2);
            }
            if (has_diag) {
                const int td = nfull;
                bf16x8 ka[4];
                lds_kfrag(Ks, td, row, half, ka);
                f32x16 accA = mfma_tile(ka, qf);
                expacc_diag(accA, &vt[td][0], half, row, z2, o2);
            }
        }
        float z = z2[0] + z2[1];
        float o = o2[0] + o2[1];
        z += __shfl_xor(z, 32, 64);
        o += __shfl_xor(o, 32, 64);
        if (half == 0)
            zopart[((size_t)(b * 64 + lb) * CCH + c) * 32 + row] = float2{z, o};
        #pragma unroll
        for (int kk = 0; kk < 4; ++kk) qf[kk] = qn[kk];
    }
}

// ---- combine chunks: per (b,lb,col) -> o/z, block-reduce to 512 partials ----
__global__ __launch_bounds__(256) void attn_combine(const float2* __restrict__ zopart,
                                                    float* __restrict__ partials) {
    __shared__ float red[256];
    const int t = threadIdx.x;
    const int e = blockIdx.x * 256 + t;
    const int bl = e >> 5, col = e & 31;
    float z = 0.f, o = 0.f;
    #pragma unroll
    for (int c = 0; c < CCH; ++c) {
        float2 p = zopart[((size_t)bl * CCH + c) * 32 + col];
        z += p.x; o += p.y;
    }
    red[t] = o / z;
    __syncthreads();
    for (int sh = 128; sh > 0; sh >>= 1) {
        if (t < sh) red[t] += red[t + sh];
        __syncthreads();
    }
    if (t == 0) partials[blockIdx.x] = red[0];
}

// ---- final deterministic reduction of 512 partials ----
__global__ void reduce_kernel(const float* __restrict__ partials, float* __restrict__ out) {
    __shared__ float red[256];
    int t = threadIdx.x;
    red[t] = partials[t] + partials[t + 256];
    __syncthreads();
    for (int sh = 128; sh > 0; sh >>= 1) {
        if (t < sh) red[t] += red[t + sh];
        __syncthreads();
    }
    if (t == 0) out[0] = red[0];
}

extern "C" void kernel_launch(void* const* d_in, const int* in_sizes, int n_in,
                              void* d_out, int out_size, void* d_ws, size_t ws_size,
                              hipStream_t stream) {
    const float* x    = (const float*)d_in[0];
    const float* wqkv = (const float*)d_in[1];
    const float* wout = (const float*)d_in[2];
    float* out = (float*)d_out;

    unsigned short* qws = (unsigned short*)d_ws;
    unsigned short* kws = qws + (size_t)BH * LSEQ * DH;
    unsigned short* xb  = kws + (size_t)BH * LSEQ * DH;
    unsigned short* wb  = xb + (size_t)LSEQ * NB * EMB;
    float* vw       = (float*)(wb + (size_t)2 * EMB * EMB);
    float* wveff    = vw + (size_t)BH * LSEQ;
    float* partials = wveff + NH * EMB;
    float* wpart    = partials + 1024;
    // zopart (8.4 MB) aliases xb (16 MB): proj_mfma (the only xb reader)
    // completes before attn_mfma writes; xb is rewritten every call (by vw).
    float2* zopart  = (float2*)xb;

    hipLaunchKernelGGL(prep_kernel,   dim3(1024 + 128), dim3(256), 0, stream,
                       wqkv, wout, wb, wpart);
    hipLaunchKernelGGL(wveff_kernel,  dim3(NH * 4), dim3(256), 0, stream, wqkv, wpart, wveff);
    hipLaunchKernelGGL(vw_kernel,     dim3(LSEQ * NB / 16), dim3(256), 0, stream, x, wveff, vw, xb);
    hipLaunchKernelGGL(proj_mfma,     dim3(1024), dim3(512), 0, stream,
                       xb, wb, qws, kws);
    hipLaunchKernelGGL(attn_mfma,     dim3(BH * CCH), dim3(512), 0, stream,
                       qws, kws, vw, zopart);
    hipLaunchKernelGGL(attn_combine,  dim3(512), dim3(256), 0, stream, zopart, partials);
    hipLaunchKernelGGL(reduce_kernel, dim3(1), dim3(256), 0, stream, partials, out);
}